// Round 12
// baseline (1711.224 us; speedup 1.0000x reference)
//
#include <hip/hip_runtime.h>

#define NN 50000
#define NE 800000
#define HID 128
#define NG 2500
#define NL 4
#define ME 64       // edges (or nodes) per block
#define HST 136     // LDS tile row stride (shorts): 272B, bank-phase 4 -> 2-way max (free)
#define NPB 782     // node blocks: ceil(50000/64)
#define NWG (NE/ME) // 12500 max edge blocks (device-side early exit past Na)
#define NIB 391     // inactive-edge blocks: ceil(NE/8/256)

typedef __attribute__((ext_vector_type(8))) short short8v;
typedef __attribute__((ext_vector_type(4))) float f32x4;

__device__ __forceinline__ float sigf(float x){ return 1.0f/(1.0f+__expf(-x)); }
__device__ __forceinline__ float siluf(float x){ return x/(1.0f+__expf(-x)); }
__device__ __forceinline__ short bfr(float x){           // scalar f32->bf16 (RNE)
  unsigned u = __float_as_uint(x);
  u += 0x7fffu + ((u>>16)&1u);
  return (short)(u>>16);
}
__device__ __forceinline__ unsigned cvtpk(float lo, float hi){
  unsigned r;
  asm("v_cvt_pk_bf16_f32 %0, %1, %2" : "=v"(r) : "v"(lo), "v"(hi));
  return r;
}
__device__ __forceinline__ float bf2f(short s){
  return __uint_as_float(((unsigned)(unsigned short)s)<<16);
}

// ------------- partitioned counting sort of edges by col (active = mask 1) -------------
__global__ void hist2_kernel(const int* __restrict__ eidx, const float* __restrict__ p,
                             const int* __restrict__ inv,
                             int* __restrict__ histA, int* __restrict__ histI){
  int e = blockIdx.x*256 + threadIdx.x;
  if (e < NE){
    int c = eidx[NE+e];
    if (p[inv[e]] >= 0.0f) atomicAdd(&histA[c], 1);
    else                   atomicAdd(&histI[c], 1);
  }
}
// in-place exclusive scan over NN entries; writes total to cursor[NN]
__global__ __launch_bounds__(1024) void scan_kernel(int* __restrict__ cursor){
  __shared__ int part[1024];
  int t = threadIdx.x;
  const int CH = (NN + 1023)/1024;
  int base = t*CH;
  int s = 0;
  for (int j=0;j<CH;++j){ int i=base+j; if (i<NN) s += cursor[i]; }
  part[t] = s; __syncthreads();
  for (int d=1; d<1024; d<<=1){
    int v = (t>=d) ? part[t-d] : 0;
    __syncthreads();
    part[t] += v;
    __syncthreads();
  }
  int ex = (t==0) ? 0 : part[t-1];
  for (int j=0;j<CH;++j){
    int i=base+j;
    if (i<NN){ int hv = cursor[i]; cursor[i] = ex; ex += hv; }
  }
  if (t == 1023) cursor[NN] = part[1023];   // total
}
// fused scatter + stream materialization into active / inactive sorted streams
__global__ void scatter2_kernel(const int* __restrict__ eidx, const float* __restrict__ p,
                                const int* __restrict__ inv, const float* __restrict__ ea,
                                int* __restrict__ curA, int* __restrict__ curI,
                                int2* __restrict__ rcA, float4* __restrict__ eaA,
                                int2* __restrict__ rcI){
  int e = blockIdx.x*256 + threadIdx.x;
  if (e >= NE) return;
  int r = eidx[e], c = eidx[NE+e];
  int2 rc; rc.x = r; rc.y = c;
  if (p[inv[e]] >= 0.0f){
    int pos = atomicAdd(&curA[c], 1);
    rcA[pos] = rc;
    eaA[pos] = *reinterpret_cast<const float4*>(ea + (size_t)e*4);
  } else {
    int pos = atomicAdd(&curI[c], 1);
    rcI[pos] = rc;
  }
}
// pad active stream to a multiple of 64 with dummy edges pointing at dump row NN
__global__ void pad_kernel(const int* __restrict__ naT, int2* __restrict__ rcA,
                           float4* __restrict__ eaA){
  int Na = naT[0];
  int NaP = (Na + 63) & ~63;
  int i = Na + threadIdx.x;
  if (i < NaP){
    int2 rc; rc.x = 0; rc.y = NN;   // row 0 (valid), col NN (dump row)
    rcA[i] = rc;
    float4 zz; zz.x=0.f; zz.y=0.f; zz.z=0.f; zz.w=0.f;
    eaA[i] = zz;
  }
}
// per-layer constant cw for masked edges: silu(bc1) . Wc2 + cb2 (f32 exact)
__global__ void cwc_kernel(const float* __restrict__ cb1, const float* __restrict__ cW2,
                           const float* __restrict__ cb2, float* __restrict__ cwc){
  int l = blockIdx.x, o = threadIdx.x;   // 128 threads
  float v = siluf(cb1[l*HID+o]) * cW2[l*HID+o];
  #pragma unroll
  for (int off=32; off>0; off>>=1) v += __shfl_down(v, off);
  __shared__ float red[2];
  if ((o & 63) == 0) red[o>>6] = v;
  __syncthreads();
  if (o == 0) cwc[l] = red[0] + red[1] + cb2[l];
}

// ---- weight prepack: rows [roff,roff+128) of [L][Ktot][128] -> [L][ks4][q4][o128][kk8] bf16
__global__ void prepack_kernel(const float* __restrict__ W, short* __restrict__ out,
                               int Ktot, int roff){
  int idx = blockIdx.x*256 + threadIdx.x;
  if (idx >= NL*4*4*HID*8) return;
  int kk8 = idx & 7;
  int o   = (idx>>3) & 127;
  int q   = (idx>>10) & 3;
  int ks  = (idx>>12) & 3;
  int l   = idx >> 14;
  int k = roff + ks*32 + q*8 + kk8;
  float v = (k < Ktot) ? W[((size_t)l*Ktot + k)*HID + o] : 0.0f;
  out[idx] = bfr(v);
}

__global__ void embed_kernel(const float* __restrict__ xf, const float* __restrict__ W,
                             const float* __restrict__ b, float* __restrict__ h){
  int n = blockIdx.x; int o = threadIdx.x;
  float s = b[o];
  #pragma unroll
  for (int i=0;i<11;++i) s = fmaf(xf[n*11+i], W[i*HID+o], s);
  h[(size_t)n*HID+o] = s;
}

// ---------------- MFMA tile-GEMM: [64 x 128] (LDS bf16) @ [128 x 128] (prepacked) ----
__device__ __forceinline__ void gemm64(const short* As, int astride,
                                       const short* Wp, int nks,
                                       short* bkS, f32x4 acc[2][4], int t)
{
  const int lane = t & 63, w = t >> 6;
  const int q = lane >> 4, fr = lane & 15;
  const int erow = (w & 1) * 32;
  const int ocol = (w >> 1) * 64;
  const int4* g = reinterpret_cast<const int4*>(Wp);
  int4* bkw = reinterpret_cast<int4*>(bkS);
  int4 p0 = g[t], p1 = g[256 + t];
  for (int ks = 0; ks < nks; ++ks){
    const int buf = (ks & 1) * 512;            // int4 units (4096 shorts)
    bkw[buf + t] = p0; bkw[buf + 256 + t] = p1;
    __syncthreads();
    if (ks + 1 < nks){ p0 = g[(ks+1)*512 + t]; p1 = g[(ks+1)*512 + 256 + t]; }
    const short* bb = bkS + buf*8 + q*1024;
    short8v a[2], b[4];
    #pragma unroll
    for (int et=0; et<2; ++et)
      a[et] = *reinterpret_cast<const short8v*>(As + (erow + et*16 + fr)*astride + ks*32 + q*8);
    #pragma unroll
    for (int ot=0; ot<4; ++ot)
      b[ot] = *reinterpret_cast<const short8v*>(bb + (ocol + ot*16 + fr)*8);
    #pragma unroll
    for (int et=0; et<2; ++et)
      #pragma unroll
      for (int ot=0; ot<4; ++ot)
        acc[et][ot] = __builtin_amdgcn_mfma_f32_16x16x32_bf16(a[et], b[ot], acc[et][ot], 0, 0, 0);
  }
  __syncthreads();
}

// acc -> silu(scale*acc + bias) -> bf16 LDS tile [64][HST]; scaleS==nullptr -> scale=1
__device__ __forceinline__ void epilogue_store(const f32x4 acc[2][4],
                                               const float* __restrict__ bias,
                                               const float* __restrict__ scaleS,
                                               short* dst, int t)
{
  const int lane = t & 63, w = t >> 6;
  const int q = lane >> 4, fr = lane & 15;
  #pragma unroll
  for (int et=0; et<2; ++et){
    const int e0 = (w&1)*32 + et*16 + q*4;
    float s0=1.f,s1=1.f,s2=1.f,s3=1.f;
    if (scaleS){ s0=scaleS[e0]; s1=scaleS[e0+1]; s2=scaleS[e0+2]; s3=scaleS[e0+3]; }
    #pragma unroll
    for (int ot=0; ot<4; ++ot){
      int o = (w>>1)*64 + ot*16 + fr;
      float bv = bias[o];
      unsigned p01 = cvtpk(siluf(fmaf(s0,acc[et][ot][0],bv)), siluf(fmaf(s1,acc[et][ot][1],bv)));
      unsigned p23 = cvtpk(siluf(fmaf(s2,acc[et][ot][2],bv)), siluf(fmaf(s3,acc[et][ot][3],bv)));
      dst[(e0+0)*HST + o] = (short)p01;
      dst[(e0+1)*HST + o] = (short)(p01>>16);
      dst[(e0+2)*HST + o] = (short)p23;
      dst[(e0+3)*HST + o] = (short)(p23>>16);
    }
  }
}

// ---------------- layer-0 node projections: A = bf16(h@W1hc + b1), B = bf16(h@W1hr) ----
__global__ __launch_bounds__(256) void nodeproj_kernel(
    const float* __restrict__ h,
    const short* __restrict__ Wcp, const float* __restrict__ b1,
    const short* __restrict__ Wrp,
    short* __restrict__ A, short* __restrict__ B)
{
  __shared__ __align__(16) short hT[ME*HST];
  __shared__ __align__(16) short bkS[2*4096];
  const int t = threadIdx.x;
  const int n0 = blockIdx.x * ME;
  {
    int nl = t >> 2, seg = t & 3;
    int n = n0 + nl; if (n >= NN) n = NN-1;
    const float4* hp = reinterpret_cast<const float4*>(h + (size_t)n*HID + seg*32);
    #pragma unroll
    for (int bq=0;bq<4;++bq){
      float4 u = hp[bq*2], v = hp[bq*2+1];
      int4 sv;
      sv.x = (int)cvtpk(u.x,u.y); sv.y = (int)cvtpk(u.z,u.w);
      sv.z = (int)cvtpk(v.x,v.y); sv.w = (int)cvtpk(v.z,v.w);
      *reinterpret_cast<int4*>(&hT[nl*HST + seg*32 + bq*8]) = sv;
    }
  }
  f32x4 z = {0.f,0.f,0.f,0.f};
  f32x4 accA[2][4], accB[2][4];
  #pragma unroll
  for (int i=0;i<2;++i){ accA[i][0]=z;accA[i][1]=z;accA[i][2]=z;accA[i][3]=z;
                         accB[i][0]=z;accB[i][1]=z;accB[i][2]=z;accB[i][3]=z; }
  gemm64(hT, HST, Wcp, 4, bkS, accA, t);
  gemm64(hT, HST, Wrp, 4, bkS, accB, t);
  const int lane = t & 63, w = t >> 6;
  const int q = lane >> 4, fr = lane & 15;
  #pragma unroll
  for (int et=0; et<2; ++et){
    int e0 = (w&1)*32 + et*16 + q*4;
    #pragma unroll
    for (int ot=0; ot<4; ++ot){
      int o = (w>>1)*64 + ot*16 + fr;
      float bv = b1[o];
      #pragma unroll
      for (int r=0;r<4;++r){
        int n = n0 + e0 + r;
        if (n < NN){
          A[(size_t)n*HID + o] = bfr(accA[et][ot][r] + bv);
          B[(size_t)n*HID + o] = bfr(accB[et][ot][r]);
        }
      }
    }
  }
}

// ---------------- edge kernel (R6/R11 structure; ACTIVE edges only) ----------------
__global__ __launch_bounds__(256) void edge2_kernel(
    const short* __restrict__ A, const short* __restrict__ B,
    const float* __restrict__ x,
    const int2* __restrict__ rcS, const float4* __restrict__ eaS,
    const int* __restrict__ naT,
    const float* __restrict__ wrow,   // eW1 + l*261*128 : rows 256..260 = wd, wea
    const short* __restrict__ W2p, const float* __restrict__ b2,
    const float* __restrict__ Wg, const float* __restrict__ bg,
    const short* __restrict__ C1p, const float* __restrict__ bc1,
    const float* __restrict__ Wc2, const float* __restrict__ cb2,
    float* __restrict__ magg, float* __restrict__ xout)
{
  __shared__ __align__(16) short hidS[ME*HST];   // hidden1 -> m_pre (kept) -> hidden2
  __shared__ __align__(16) short bkS[2*4096];
  __shared__ float wdS[HID], wgS[HID], wc2S[HID];
  __shared__ float weaS[4][HID];
  __shared__ float scaleS[ME], cwS[ME], distS[ME], cdS[ME][3];
  __shared__ int colS[ME];

  const int t = threadIdx.x;
  // bijective XCD swizzle (m204)
  const int xcd = blockIdx.x & 7, sub = blockIdx.x >> 3;
  const int qq = NWG >> 3, rr = NWG & 7;
  const int bid = (xcd < rr ? xcd*(qq+1) : rr*(qq+1) + (xcd-rr)*qq) + sub;
  const int i0 = bid * ME;
  const int NaP = (naT[0] + 63) & ~63;
  if (i0 >= NaP) return;                 // past the active stream: nothing to do

  // issue per-thread gathers early (4 threads/edge, 32 channels each)
  const int el = t >> 2, seg = t & 3;
  const int2 rc = rcS[i0 + el];
  const int4* Ap = reinterpret_cast<const int4*>(A + (size_t)rc.y*HID + seg*32);
  const int4* Bp = reinterpret_cast<const int4*>(B + (size_t)rc.x*HID + seg*32);
  int4 av0=Ap[0], av1=Ap[1], av2=Ap[2], av3=Ap[3];
  int4 bv0=Bp[0], bv1=Bp[1], bv2=Bp[2], bv3=Bp[3];
  float4 eav = eaS[i0 + el];

  if (t < HID){
    wdS[t] = wrow[256*HID + t];
    wgS[t] = Wg[t]; wc2S[t] = Wc2[t];
    #pragma unroll
    for (int j=0;j<4;++j) weaS[j][t] = wrow[(257+j)*HID + t];
  }
  if (t < ME){
    int2 rc2 = rcS[i0 + t];
    colS[t] = rc2.y;
    float dx = x[rc2.y*3+0]-x[rc2.x*3+0];
    float dy = x[rc2.y*3+1]-x[rc2.x*3+1];
    float dz = x[rc2.y*3+2]-x[rc2.x*3+2];
    cdS[t][0]=dx; cdS[t][1]=dy; cdS[t][2]=dz;
    distS[t] = sqrtf(dx*dx+dy*dy+dz*dz);
  }
  __syncthreads();

  // hidden1 = silu(A[col] + B[row] + dist*wd + ea@wea)
  {
    float de = distS[el];
    const int4 avs[4] = {av0,av1,av2,av3};
    const int4 bvs[4] = {bv0,bv1,bv2,bv3};
    #pragma unroll
    for (int bq=0;bq<4;++bq){
      short8v a8 = *reinterpret_cast<const short8v*>(&avs[bq]);
      short8v b8 = *reinterpret_cast<const short8v*>(&bvs[bq]);
      float f[8];
      #pragma unroll
      for (int j=0;j<8;++j){
        int o = seg*32 + bq*8 + j;
        float v = bf2f(a8[j]) + bf2f(b8[j]) + de*wdS[o]
                + eav.x*weaS[0][o] + eav.y*weaS[1][o]
                + eav.z*weaS[2][o] + eav.w*weaS[3][o];
        f[j] = siluf(v);
      }
      int4 sv;
      sv.x = (int)cvtpk(f[0],f[1]); sv.y = (int)cvtpk(f[2],f[3]);
      sv.z = (int)cvtpk(f[4],f[5]); sv.w = (int)cvtpk(f[6],f[7]);
      *reinterpret_cast<int4*>(&hidS[el*HST + seg*32 + bq*8]) = sv;
    }
  }
  // gemm64's first loop-top barrier publishes hidS

  f32x4 z = {0.f,0.f,0.f,0.f};
  f32x4 acc2[2][4];
  #pragma unroll
  for (int i=0;i<2;++i){ acc2[i][0]=z; acc2[i][1]=z; acc2[i][2]=z; acc2[i][3]=z; }
  gemm64(hidS, HST, W2p, 4, bkS, acc2, t);
  epilogue_store(acc2, b2, nullptr, hidS, t);     // m_pre (in-place)
  __syncthreads();                                // publish m_pre

  // gate = sigmoid(m_pre . Wg + bg)   (active edges: mask == 1)
  {
    int eg = t >> 2, g = t & 3;
    float p = 0.f;
    #pragma unroll
    for (int bq=0;bq<4;++bq){
      short8v s = *reinterpret_cast<const short8v*>(&hidS[eg*HST + g*32 + bq*8]);
      #pragma unroll
      for (int j=0;j<8;++j) p += bf2f(s[j]) * wgS[g*32 + bq*8 + j];
    }
    p += __shfl_xor(p, 1); p += __shfl_xor(p, 2);
    if (g == 0) scaleS[eg] = sigf(p + bg[0]);
  }
  __syncthreads();                                // publish scaleS

  // magg[col] += m_pre * scale (segmented; cols sorted)
  {
    int o = t & 127, half = t >> 7;
    int ib = half*32;
    float accv = 0.f;
    int curc = colS[ib];
    #pragma unroll 4
    for (int j=0;j<32;++j){
      int i = ib + j;
      int cc = colS[i];
      if (cc != curc){
        atomicAdd(&magg[(size_t)curc*HID + o], accv);
        accv = 0.f; curc = cc;
      }
      accv += bf2f(hidS[i*HST + o]) * scaleS[i];
    }
    atomicAdd(&magg[(size_t)curc*HID + o], accv);
  }

  // hidden2 = silu(scale * (m_pre @ Wc1) + bc1)
  f32x4 acc3[2][4];
  #pragma unroll
  for (int i=0;i<2;++i){ acc3[i][0]=z; acc3[i][1]=z; acc3[i][2]=z; acc3[i][3]=z; }
  gemm64(hidS, HST, C1p, 4, bkS, acc3, t);
  epilogue_store(acc3, bc1, scaleS, hidS, t);     // hidden2 (in-place)
  __syncthreads();                                // publish hidden2

  // cw = hidden2 . Wc2 + cb2
  {
    int eg = t >> 2, g = t & 3;
    float p = 0.f;
    #pragma unroll
    for (int bq=0;bq<4;++bq){
      short8v s = *reinterpret_cast<const short8v*>(&hidS[eg*HST + g*32 + bq*8]);
      #pragma unroll
      for (int j=0;j<8;++j) p += bf2f(s[j]) * wc2S[g*32 + bq*8 + j];
    }
    p += __shfl_xor(p, 1); p += __shfl_xor(p, 2);
    if (g == 0) cwS[eg] = p + cb2[0];
  }
  __syncthreads();                                // publish cwS

  // x_out[col] += coord_diff * cw (segmented)
  if (t < 6){
    int d = t % 3, half = t / 3;
    int ib = half*32;
    float accx = 0.f;
    int curc = colS[ib];
    for (int j=0;j<32;++j){
      int i = ib + j;
      int cc = colS[i];
      if (cc != curc){
        atomicAdd(&xout[curc*3+d], accx);
        accx = 0.f; curc = cc;
      }
      accx += cdS[i][d] * cwS[i];
    }
    atomicAdd(&xout[curc*3+d], accx);
  }
}

// ---- inactive edges: xout[col] += coord_diff * cw_const[l] (8 sorted edges/thread) ----
__global__ void inact_kernel(const int* __restrict__ niT, const int2* __restrict__ rcI,
                             const float* __restrict__ x, const float* __restrict__ cwc,
                             int l, float* __restrict__ xout){
  int Ni = niT[0];
  int base = (blockIdx.x*256 + threadIdx.x)*8;
  if (base >= Ni) return;
  const float cw = cwc[l];
  int end = base + 8; if (end > Ni) end = Ni;
  int curc = rcI[base].y;
  float ax=0.f, ay=0.f, az=0.f;
  for (int i=base;i<end;++i){
    int2 rc = rcI[i];
    if (rc.y != curc){
      atomicAdd(&xout[curc*3+0], ax);
      atomicAdd(&xout[curc*3+1], ay);
      atomicAdd(&xout[curc*3+2], az);
      ax=0.f; ay=0.f; az=0.f; curc = rc.y;
    }
    float dx = x[rc.y*3+0]-x[rc.x*3+0];
    float dy = x[rc.y*3+1]-x[rc.x*3+1];
    float dz = x[rc.y*3+2]-x[rc.x*3+2];
    ax = fmaf(dx,cw,ax); ay = fmaf(dy,cw,ay); az = fmaf(dz,cw,az);
  }
  atomicAdd(&xout[curc*3+0], ax);
  atomicAdd(&xout[curc*3+1], ay);
  atomicAdd(&xout[curc*3+2], az);
}

// ---- fused node MLP + next-layer projections ----
__global__ __launch_bounds__(256) void node2f_kernel(
    float* __restrict__ h, const float* __restrict__ magg,
    const short* __restrict__ W1ap, const short* __restrict__ W1bp,
    const float* __restrict__ bn1,
    const short* __restrict__ Wn2p, const float* __restrict__ bn2,
    const short* __restrict__ Wcp, const float* __restrict__ b1n,
    const short* __restrict__ Wrp,
    short* __restrict__ A, short* __restrict__ B, int doProj)
{
  __shared__ __align__(16) short hT[ME*HST];
  __shared__ __align__(16) short mT[ME*HST];
  __shared__ __align__(16) short bkS[2*4096];
  const int t = threadIdx.x;
  const int n0 = blockIdx.x * ME;
  {
    int nl = t >> 2, seg = t & 3;
    int n = n0 + nl; if (n >= NN) n = NN-1;
    const float4* hp = reinterpret_cast<const float4*>(h + (size_t)n*HID + seg*32);
    const float4* mp = reinterpret_cast<const float4*>(magg + (size_t)n*HID + seg*32);
    #pragma unroll
    for (int bq=0;bq<4;++bq){
      float4 u = hp[bq*2], v = hp[bq*2+1];
      int4 sv;
      sv.x = (int)cvtpk(u.x,u.y); sv.y = (int)cvtpk(u.z,u.w);
      sv.z = (int)cvtpk(v.x,v.y); sv.w = (int)cvtpk(v.z,v.w);
      *reinterpret_cast<int4*>(&hT[nl*HST + seg*32 + bq*8]) = sv;
      float4 u2 = mp[bq*2], v2 = mp[bq*2+1];
      int4 sv2;
      sv2.x = (int)cvtpk(u2.x,u2.y); sv2.y = (int)cvtpk(u2.z,u2.w);
      sv2.z = (int)cvtpk(v2.x,v2.y); sv2.w = (int)cvtpk(v2.z,v2.w);
      *reinterpret_cast<int4*>(&mT[nl*HST + seg*32 + bq*8]) = sv2;
    }
  }
  f32x4 z = {0.f,0.f,0.f,0.f};
  f32x4 acc[2][4];
  #pragma unroll
  for (int i=0;i<2;++i){ acc[i][0]=z; acc[i][1]=z; acc[i][2]=z; acc[i][3]=z; }
  gemm64(hT, HST, W1ap, 4, bkS, acc, t);
  gemm64(mT, HST, W1bp, 4, bkS, acc, t);        // accumulates
  epilogue_store(acc, bn1, nullptr, mT, t);      // silu1 -> mT
  __syncthreads();

  f32x4 acc2[2][4];
  #pragma unroll
  for (int i=0;i<2;++i){ acc2[i][0]=z; acc2[i][1]=z; acc2[i][2]=z; acc2[i][3]=z; }
  gemm64(mT, HST, Wn2p, 4, bkS, acc2, t);

  const int lane = t & 63, w = t >> 6;
  const int q = lane >> 4, fr = lane & 15;
  #pragma unroll
  for (int et=0; et<2; ++et){
    int e0 = (w&1)*32 + et*16 + q*4;
    #pragma unroll
    for (int ot=0; ot<4; ++ot){
      int o = (w>>1)*64 + ot*16 + fr;
      float bv = bn2[o];
      float hn[4];
      #pragma unroll
      for (int r=0;r<4;++r){
        int n = n0 + e0 + r;
        float hv = 0.f;
        if (n < NN){
          size_t idx = (size_t)n*HID + o;
          hv = h[idx] + acc2[et][ot][r] + bv;
          h[idx] = hv;
        }
        hn[r] = hv;
      }
      if (doProj){
        unsigned p01 = cvtpk(hn[0],hn[1]), p23 = cvtpk(hn[2],hn[3]);
        hT[(e0+0)*HST + o] = (short)p01;
        hT[(e0+1)*HST + o] = (short)(p01>>16);
        hT[(e0+2)*HST + o] = (short)p23;
        hT[(e0+3)*HST + o] = (short)(p23>>16);
      }
    }
  }
  if (!doProj) return;
  // (gemm64's loop-top barrier publishes hT)

  f32x4 accA[2][4], accB[2][4];
  #pragma unroll
  for (int i=0;i<2;++i){ accA[i][0]=z;accA[i][1]=z;accA[i][2]=z;accA[i][3]=z;
                         accB[i][0]=z;accB[i][1]=z;accB[i][2]=z;accB[i][3]=z; }
  gemm64(hT, HST, Wcp, 4, bkS, accA, t);
  gemm64(hT, HST, Wrp, 4, bkS, accB, t);
  #pragma unroll
  for (int et=0; et<2; ++et){
    int e0 = (w&1)*32 + et*16 + q*4;
    #pragma unroll
    for (int ot=0; ot<4; ++ot){
      int o = (w>>1)*64 + ot*16 + fr;
      float bv = b1n[o];
      #pragma unroll
      for (int r=0;r<4;++r){
        int n = n0 + e0 + r;
        if (n < NN){
          A[(size_t)n*HID + o] = bfr(accA[et][ot][r] + bv);
          B[(size_t)n*HID + o] = bfr(accB[et][ot][r]);
        }
      }
    }
  }
}

__global__ void pool_kernel(const float* __restrict__ h, const int* __restrict__ batch,
                            float* __restrict__ sums, float* __restrict__ counts){
  int o  = threadIdx.x;
  int n0 = blockIdx.x * 16;
  int curg = batch[n0];
  float accv = 0.f, cnt = 0.f;
  for (int j=0;j<16;++j){
    int n = n0 + j;
    int g = batch[n];
    if (g != curg){
      atomicAdd(&sums[(size_t)curg*HID+o], accv);
      if (o==0) atomicAdd(&counts[curg], cnt);
      accv = 0.f; cnt = 0.f; curg = g;
    }
    accv += h[(size_t)n*HID+o];
    cnt  += 1.f;
  }
  atomicAdd(&sums[(size_t)curg*HID+o], accv);
  if (o==0) atomicAdd(&counts[curg], cnt);
}

__global__ void out_kernel(const float* __restrict__ sums, const float* __restrict__ counts,
                           const float* __restrict__ rW, const float* __restrict__ rb,
                           float* __restrict__ out){
  int g = blockIdx.x; int t = threadIdx.x;
  float v = sums[(size_t)g*HID + t]*rW[t] + sums[(size_t)g*HID + 64 + t]*rW[64+t];
  #pragma unroll
  for (int off=32; off>0; off>>=1) v += __shfl_down(v, off);
  if (t==0) out[g] = v / fmaxf(counts[g], 1.0f) + rb[0];
}

extern "C" void kernel_launch(void* const* d_in, const int* in_sizes, int n_in,
                              void* d_out, int out_size, void* d_ws, size_t ws_size,
                              hipStream_t stream)
{
  const float* x_feat = (const float*)d_in[0];
  const float* pos    = (const float*)d_in[1];
  const float* eattr  = (const float*)d_in[2];
  const float* p      = (const float*)d_in[3];
  const float* embW   = (const float*)d_in[4];
  const float* embB   = (const float*)d_in[5];
  const float* eW1    = (const float*)d_in[6];
  const float* eb1    = (const float*)d_in[7];
  const float* eW2    = (const float*)d_in[8];
  const float* eb2    = (const float*)d_in[9];
  const float* gW     = (const float*)d_in[10];
  const float* gb     = (const float*)d_in[11];
  const float* nW1    = (const float*)d_in[12];
  const float* nb1    = (const float*)d_in[13];
  const float* nW2    = (const float*)d_in[14];
  const float* nb2    = (const float*)d_in[15];
  const float* cW1    = (const float*)d_in[16];
  const float* cb1    = (const float*)d_in[17];
  const float* cW2    = (const float*)d_in[18];
  const float* cb2    = (const float*)d_in[19];
  const float* rW     = (const float*)d_in[20];
  const float* rb     = (const float*)d_in[21];
  const int* eidx     = (const int*)d_in[22];
  const int* einv     = (const int*)d_in[23];
  const int* batch    = (const int*)d_in[24];

  float* ws = (float*)d_ws;
  float* h      = ws;  ws += (size_t)NN*HID;
  float* magg   = ws;  ws += (size_t)(NN+1)*HID;       // +dump row
  float* xA     = ws;  ws += (size_t)(NN+1)*3;         // +dump row
  float* xB     = ws;  ws += (size_t)(NN+1)*3;
  float* sums   = ws;  ws += (size_t)NG*HID;
  float* counts = ws;  ws += NG;
  float* cwc    = ws;  ws += 4;
  int*   histA  = (int*)ws;  ws += NN+1;               // [NN] = Na
  int*   histI  = (int*)ws;  ws += NN+1;               // [NN] = Ni
  int2*  rcA    = (int2*)ws;  ws += (size_t)NE*2;
  int2*  rcI    = (int2*)ws;  ws += (size_t)NE*2;
  float4* eaA   = (float4*)ws; ws += (size_t)NE*4;
  short* Abuf = (short*)ws;  ws += (size_t)(NN+1)*HID/2;   // +dump row
  short* Bbuf = (short*)ws;  ws += (size_t)(NN+1)*HID/2;
  const size_t PK = (size_t)NL*4*4*HID*8;   // shorts per packed array
  short* W1cp  = (short*)ws;
  short* W1rp  = W1cp  + PK;
  short* W2p   = W1rp  + PK;
  short* C1p   = W2p   + PK;
  short* Wn1ap = C1p   + PK;
  short* Wn1bp = Wn1ap + PK;
  short* Wn2p  = Wn1bp + PK;

  // partitioned counting sort by col: active (mask=1) and inactive streams
  hipMemsetAsync(histA, 0, sizeof(int)*2*(NN+1), stream);
  hist2_kernel<<<(NE+255)/256, 256, 0, stream>>>(eidx, p, einv, histA, histI);
  scan_kernel<<<1, 1024, 0, stream>>>(histA);
  scan_kernel<<<1, 1024, 0, stream>>>(histI);
  scatter2_kernel<<<(NE+255)/256, 256, 0, stream>>>(eidx, p, einv, eattr,
                                                    histA, histI, rcA, eaA, rcI);
  pad_kernel<<<1, 64, 0, stream>>>(histA + NN, rcA, eaA);
  cwc_kernel<<<NL, 128, 0, stream>>>(cb1, cW2, cb2, cwc);

  // prepack bf16 weights (each [L][4][4][128][8])
  const int PG = (int)((PK + 255)/256);
  prepack_kernel<<<PG, 256, 0, stream>>>(eW1, W1cp, 261, 0);
  prepack_kernel<<<PG, 256, 0, stream>>>(eW1, W1rp, 261, 128);
  prepack_kernel<<<PG, 256, 0, stream>>>(eW2, W2p, 128, 0);
  prepack_kernel<<<PG, 256, 0, stream>>>(cW1, C1p, 128, 0);
  prepack_kernel<<<PG, 256, 0, stream>>>(nW1, Wn1ap, 256, 0);
  prepack_kernel<<<PG, 256, 0, stream>>>(nW1, Wn1bp, 256, 128);
  prepack_kernel<<<PG, 256, 0, stream>>>(nW2, Wn2p, 128, 0);

  hipMemcpyAsync(xA, pos, sizeof(float)*NN*3, hipMemcpyDeviceToDevice, stream);
  embed_kernel<<<NN, HID, 0, stream>>>(x_feat, embW, embB, h);
  // layer-0 projections
  nodeproj_kernel<<<NPB, 256, 0, stream>>>(h, W1cp, eb1, W1rp, Abuf, Bbuf);

  float* xc = xA; float* xn = xB;
  for (int l=0;l<NL;++l){
    const size_t wofs = (size_t)l*4*4096;
    const size_t wofsn = (size_t)(l+1)*4*4096;
    hipMemsetAsync(magg, 0, sizeof(float)*(size_t)NN*HID, stream);
    hipMemcpyAsync(xn, xc, sizeof(float)*NN*3, hipMemcpyDeviceToDevice, stream);
    edge2_kernel<<<NWG, 256, 0, stream>>>(Abuf, Bbuf, xc, rcA, eaA, histA + NN,
        eW1 + (size_t)l*261*HID,
        W2p + wofs, eb2 + l*HID,
        gW  + l*HID, gb + l,
        C1p + wofs, cb1 + l*HID,
        cW2 + l*HID, cb2 + l,
        magg, xn);
    inact_kernel<<<NIB, 256, 0, stream>>>(histI + NN, rcI, xc, cwc, l, xn);
    int doProj = (l+1 < NL);
    node2f_kernel<<<NPB, 256, 0, stream>>>(h, magg,
        Wn1ap + wofs, Wn1bp + wofs, nb1 + l*HID,
        Wn2p + wofs, nb2 + l*HID,
        W1cp + (doProj?wofsn:0), eb1 + (doProj?(l+1)*HID:0),
        W1rp + (doProj?wofsn:0),
        Abuf, Bbuf, doProj);
    float* tmp = xc; xc = xn; xn = tmp;
  }
  hipMemsetAsync(sums, 0, sizeof(float)*((size_t)NG*HID + NG), stream);
  pool_kernel<<<NN/16, HID, 0, stream>>>(h, batch, sums, counts);
  out_kernel<<<NG, 64, 0, stream>>>(sums, counts, rW, rb, (float*)d_out);
}

// Round 13
// 1231.578 us; speedup vs baseline: 1.3895x; 1.3895x over previous
//
#include <hip/hip_runtime.h>

#define NN 50000
#define NE 800000
#define HID 128
#define NG 2500
#define NL 4
#define ME 64       // edges (or nodes) per block
#define HST 136     // LDS tile row stride (shorts): 272B, bank-phase 4 -> 2-way max (free)
#define NPB 782     // node blocks: ceil(50000/64)
#define NWG (NE/ME) // 12500 max edge blocks (device-side early exit past Na)
#define NIB 391     // inactive-edge blocks: ceil(NE/8/256)

typedef __attribute__((ext_vector_type(8))) short short8v;
typedef __attribute__((ext_vector_type(4))) float f32x4;

__device__ __forceinline__ float sigf(float x){ return 1.0f/(1.0f+__expf(-x)); }
__device__ __forceinline__ float siluf(float x){ return x/(1.0f+__expf(-x)); }
__device__ __forceinline__ short bfr(float x){           // scalar f32->bf16 (RNE)
  unsigned u = __float_as_uint(x);
  u += 0x7fffu + ((u>>16)&1u);
  return (short)(u>>16);
}
__device__ __forceinline__ unsigned cvtpk(float lo, float hi){
  unsigned r;
  asm("v_cvt_pk_bf16_f32 %0, %1, %2" : "=v"(r) : "v"(lo), "v"(hi));
  return r;
}
__device__ __forceinline__ float bf2f(short s){
  return __uint_as_float(((unsigned)(unsigned short)s)<<16);
}

// ------------- partitioned counting sort of edges by col (active = mask 1) -------------
__global__ void hist2_kernel(const int* __restrict__ eidx, const float* __restrict__ p,
                             const int* __restrict__ inv,
                             int* __restrict__ histA, int* __restrict__ histI){
  int e = blockIdx.x*256 + threadIdx.x;
  if (e < NE){
    int c = eidx[NE+e];
    if (p[inv[e]] >= 0.0f) atomicAdd(&histA[c], 1);
    else                   atomicAdd(&histI[c], 1);
  }
}
// in-place exclusive scan over NN entries; writes total to cursor[NN]
__global__ __launch_bounds__(1024) void scan_kernel(int* __restrict__ cursor){
  __shared__ int part[1024];
  int t = threadIdx.x;
  const int CH = (NN + 1023)/1024;
  int base = t*CH;
  int s = 0;
  for (int j=0;j<CH;++j){ int i=base+j; if (i<NN) s += cursor[i]; }
  part[t] = s; __syncthreads();
  for (int d=1; d<1024; d<<=1){
    int v = (t>=d) ? part[t-d] : 0;
    __syncthreads();
    part[t] += v;
    __syncthreads();
  }
  int ex = (t==0) ? 0 : part[t-1];
  for (int j=0;j<CH;++j){
    int i=base+j;
    if (i<NN){ int hv = cursor[i]; cursor[i] = ex; ex += hv; }
  }
  if (t == 1023) cursor[NN] = part[1023];   // total
}
// fused scatter + stream materialization into active / inactive sorted streams
__global__ void scatter2_kernel(const int* __restrict__ eidx, const float* __restrict__ p,
                                const int* __restrict__ inv, const float* __restrict__ ea,
                                int* __restrict__ curA, int* __restrict__ curI,
                                int2* __restrict__ rcA, float4* __restrict__ eaA,
                                int2* __restrict__ rcI){
  int e = blockIdx.x*256 + threadIdx.x;
  if (e >= NE) return;
  int r = eidx[e], c = eidx[NE+e];
  int2 rc; rc.x = r; rc.y = c;
  if (p[inv[e]] >= 0.0f){
    int pos = atomicAdd(&curA[c], 1);
    rcA[pos] = rc;
    eaA[pos] = *reinterpret_cast<const float4*>(ea + (size_t)e*4);
  } else {
    int pos = atomicAdd(&curI[c], 1);
    rcI[pos] = rc;
  }
}
// pad active stream to a multiple of 64 with dummy edges pointing at dump row NN
__global__ void pad_kernel(const int* __restrict__ naT, int2* __restrict__ rcA,
                           float4* __restrict__ eaA){
  int Na = naT[0];
  int NaP = (Na + 63) & ~63;
  int i = Na + threadIdx.x;
  if (i < NaP){
    int2 rc; rc.x = 0; rc.y = NN;   // row 0 (valid), col NN (dump row)
    rcA[i] = rc;
    float4 zz; zz.x=0.f; zz.y=0.f; zz.z=0.f; zz.w=0.f;
    eaA[i] = zz;
  }
}
// per-layer constant cw for masked edges: silu(bc1) . Wc2 + cb2 (f32 exact)
__global__ void cwc_kernel(const float* __restrict__ cb1, const float* __restrict__ cW2,
                           const float* __restrict__ cb2, float* __restrict__ cwc){
  int l = blockIdx.x, o = threadIdx.x;   // 128 threads
  float v = siluf(cb1[l*HID+o]) * cW2[l*HID+o];
  #pragma unroll
  for (int off=32; off>0; off>>=1) v += __shfl_down(v, off);
  __shared__ float red[2];
  if ((o & 63) == 0) red[o>>6] = v;
  __syncthreads();
  if (o == 0) cwc[l] = red[0] + red[1] + cb2[l];
}

// ---- weight prepack: rows [roff,roff+128) of [L][Ktot][128] -> [L][ks4][q4][o128][kk8] bf16
__global__ void prepack_kernel(const float* __restrict__ W, short* __restrict__ out,
                               int Ktot, int roff){
  int idx = blockIdx.x*256 + threadIdx.x;
  if (idx >= NL*4*4*HID*8) return;
  int kk8 = idx & 7;
  int o   = (idx>>3) & 127;
  int q   = (idx>>10) & 3;
  int ks  = (idx>>12) & 3;
  int l   = idx >> 14;
  int k = roff + ks*32 + q*8 + kk8;
  float v = (k < Ktot) ? W[((size_t)l*Ktot + k)*HID + o] : 0.0f;
  out[idx] = bfr(v);
}

__global__ void embed_kernel(const float* __restrict__ xf, const float* __restrict__ W,
                             const float* __restrict__ b, float* __restrict__ h){
  int n = blockIdx.x; int o = threadIdx.x;
  float s = b[o];
  #pragma unroll
  for (int i=0;i<11;++i) s = fmaf(xf[n*11+i], W[i*HID+o], s);
  h[(size_t)n*HID+o] = s;
}

// ---------------- MFMA tile-GEMM: [64 x 128] (LDS bf16) @ [128 x 128] (prepacked) ----
__device__ __forceinline__ void gemm64(const short* As, int astride,
                                       const short* Wp, int nks,
                                       short* bkS, f32x4 acc[2][4], int t)
{
  const int lane = t & 63, w = t >> 6;
  const int q = lane >> 4, fr = lane & 15;
  const int erow = (w & 1) * 32;
  const int ocol = (w >> 1) * 64;
  const int4* g = reinterpret_cast<const int4*>(Wp);
  int4* bkw = reinterpret_cast<int4*>(bkS);
  int4 p0 = g[t], p1 = g[256 + t];
  for (int ks = 0; ks < nks; ++ks){
    const int buf = (ks & 1) * 512;            // int4 units (4096 shorts)
    bkw[buf + t] = p0; bkw[buf + 256 + t] = p1;
    __syncthreads();
    if (ks + 1 < nks){ p0 = g[(ks+1)*512 + t]; p1 = g[(ks+1)*512 + 256 + t]; }
    const short* bb = bkS + buf*8 + q*1024;
    short8v a[2], b[4];
    #pragma unroll
    for (int et=0; et<2; ++et)
      a[et] = *reinterpret_cast<const short8v*>(As + (erow + et*16 + fr)*astride + ks*32 + q*8);
    #pragma unroll
    for (int ot=0; ot<4; ++ot)
      b[ot] = *reinterpret_cast<const short8v*>(bb + (ocol + ot*16 + fr)*8);
    #pragma unroll
    for (int et=0; et<2; ++et)
      #pragma unroll
      for (int ot=0; ot<4; ++ot)
        acc[et][ot] = __builtin_amdgcn_mfma_f32_16x16x32_bf16(a[et], b[ot], acc[et][ot], 0, 0, 0);
  }
  __syncthreads();
}

// acc -> silu(scale*acc + bias) -> bf16 LDS tile [64][HST]; scaleS==nullptr -> scale=1
__device__ __forceinline__ void epilogue_store(const f32x4 acc[2][4],
                                               const float* __restrict__ bias,
                                               const float* __restrict__ scaleS,
                                               short* dst, int t)
{
  const int lane = t & 63, w = t >> 6;
  const int q = lane >> 4, fr = lane & 15;
  #pragma unroll
  for (int et=0; et<2; ++et){
    const int e0 = (w&1)*32 + et*16 + q*4;
    float s0=1.f,s1=1.f,s2=1.f,s3=1.f;
    if (scaleS){ s0=scaleS[e0]; s1=scaleS[e0+1]; s2=scaleS[e0+2]; s3=scaleS[e0+3]; }
    #pragma unroll
    for (int ot=0; ot<4; ++ot){
      int o = (w>>1)*64 + ot*16 + fr;
      float bv = bias[o];
      unsigned p01 = cvtpk(siluf(fmaf(s0,acc[et][ot][0],bv)), siluf(fmaf(s1,acc[et][ot][1],bv)));
      unsigned p23 = cvtpk(siluf(fmaf(s2,acc[et][ot][2],bv)), siluf(fmaf(s3,acc[et][ot][3],bv)));
      dst[(e0+0)*HST + o] = (short)p01;
      dst[(e0+1)*HST + o] = (short)(p01>>16);
      dst[(e0+2)*HST + o] = (short)p23;
      dst[(e0+3)*HST + o] = (short)(p23>>16);
    }
  }
}

// ---------------- layer-0 node projections: A = bf16(h@W1hc + b1), B = bf16(h@W1hr) ----
__global__ __launch_bounds__(256) void nodeproj_kernel(
    const float* __restrict__ h,
    const short* __restrict__ Wcp, const float* __restrict__ b1,
    const short* __restrict__ Wrp,
    short* __restrict__ A, short* __restrict__ B)
{
  __shared__ __align__(16) short hT[ME*HST];
  __shared__ __align__(16) short bkS[2*4096];
  const int t = threadIdx.x;
  const int n0 = blockIdx.x * ME;
  {
    int nl = t >> 2, seg = t & 3;
    int n = n0 + nl; if (n >= NN) n = NN-1;
    const float4* hp = reinterpret_cast<const float4*>(h + (size_t)n*HID + seg*32);
    #pragma unroll
    for (int bq=0;bq<4;++bq){
      float4 u = hp[bq*2], v = hp[bq*2+1];
      int4 sv;
      sv.x = (int)cvtpk(u.x,u.y); sv.y = (int)cvtpk(u.z,u.w);
      sv.z = (int)cvtpk(v.x,v.y); sv.w = (int)cvtpk(v.z,v.w);
      *reinterpret_cast<int4*>(&hT[nl*HST + seg*32 + bq*8]) = sv;
    }
  }
  f32x4 z = {0.f,0.f,0.f,0.f};
  f32x4 accA[2][4], accB[2][4];
  #pragma unroll
  for (int i=0;i<2;++i){ accA[i][0]=z;accA[i][1]=z;accA[i][2]=z;accA[i][3]=z;
                         accB[i][0]=z;accB[i][1]=z;accB[i][2]=z;accB[i][3]=z; }
  gemm64(hT, HST, Wcp, 4, bkS, accA, t);
  gemm64(hT, HST, Wrp, 4, bkS, accB, t);
  const int lane = t & 63, w = t >> 6;
  const int q = lane >> 4, fr = lane & 15;
  #pragma unroll
  for (int et=0; et<2; ++et){
    int e0 = (w&1)*32 + et*16 + q*4;
    #pragma unroll
    for (int ot=0; ot<4; ++ot){
      int o = (w>>1)*64 + ot*16 + fr;
      float bv = b1[o];
      #pragma unroll
      for (int r=0;r<4;++r){
        int n = n0 + e0 + r;
        if (n < NN){
          A[(size_t)n*HID + o] = bfr(accA[et][ot][r] + bv);
          B[(size_t)n*HID + o] = bfr(accB[et][ot][r]);
        }
      }
    }
  }
}

// ---------------- edge kernel (ACTIVE edges only; dynamic-range XCD swizzle) ----------------
__global__ __launch_bounds__(256) void edge2_kernel(
    const short* __restrict__ A, const short* __restrict__ B,
    const float* __restrict__ x,
    const int2* __restrict__ rcS, const float4* __restrict__ eaS,
    const int* __restrict__ naT,
    const float* __restrict__ wrow,   // eW1 + l*261*128 : rows 256..260 = wd, wea
    const short* __restrict__ W2p, const float* __restrict__ b2,
    const float* __restrict__ Wg, const float* __restrict__ bg,
    const short* __restrict__ C1p, const float* __restrict__ bc1,
    const float* __restrict__ Wc2, const float* __restrict__ cb2,
    float* __restrict__ magg, float* __restrict__ xout)
{
  __shared__ __align__(16) short hidS[ME*HST];   // hidden1 -> m_pre (kept) -> hidden2
  __shared__ __align__(16) short bkS[2*4096];
  __shared__ float wdS[HID], wgS[HID], wc2S[HID];
  __shared__ float weaS[4][HID];
  __shared__ float scaleS[ME], cwS[ME], distS[ME], cdS[ME][3];
  __shared__ int colS[ME];

  const int t = threadIdx.x;
  // dynamic-range bijective XCD swizzle: spread ACTIVE blocks across all XCDs (R12 bug fix)
  const int nab = (naT[0] + 63) >> 6;            // number of active blocks
  if ((int)blockIdx.x >= nab) return;
  const int qq = nab >> 3, rr = nab & 7;
  const int xcd = blockIdx.x & 7, sub = blockIdx.x >> 3;
  const int bid = (xcd < rr ? xcd*(qq+1) : rr*(qq+1) + (xcd-rr)*qq) + sub;
  const int i0 = bid * ME;

  // issue per-thread gathers early (4 threads/edge, 32 channels each)
  const int el = t >> 2, seg = t & 3;
  const int2 rc = rcS[i0 + el];
  const int4* Ap = reinterpret_cast<const int4*>(A + (size_t)rc.y*HID + seg*32);
  const int4* Bp = reinterpret_cast<const int4*>(B + (size_t)rc.x*HID + seg*32);
  int4 av0=Ap[0], av1=Ap[1], av2=Ap[2], av3=Ap[3];
  int4 bv0=Bp[0], bv1=Bp[1], bv2=Bp[2], bv3=Bp[3];
  float4 eav = eaS[i0 + el];

  if (t < HID){
    wdS[t] = wrow[256*HID + t];
    wgS[t] = Wg[t]; wc2S[t] = Wc2[t];
    #pragma unroll
    for (int j=0;j<4;++j) weaS[j][t] = wrow[(257+j)*HID + t];
  }
  if (t < ME){
    int2 rc2 = rcS[i0 + t];
    colS[t] = rc2.y;
    float dx = x[rc2.y*3+0]-x[rc2.x*3+0];
    float dy = x[rc2.y*3+1]-x[rc2.x*3+1];
    float dz = x[rc2.y*3+2]-x[rc2.x*3+2];
    cdS[t][0]=dx; cdS[t][1]=dy; cdS[t][2]=dz;
    distS[t] = sqrtf(dx*dx+dy*dy+dz*dz);
  }
  __syncthreads();

  // hidden1 = silu(A[col] + B[row] + dist*wd + ea@wea)
  {
    float de = distS[el];
    const int4 avs[4] = {av0,av1,av2,av3};
    const int4 bvs[4] = {bv0,bv1,bv2,bv3};
    #pragma unroll
    for (int bq=0;bq<4;++bq){
      short8v a8 = *reinterpret_cast<const short8v*>(&avs[bq]);
      short8v b8 = *reinterpret_cast<const short8v*>(&bvs[bq]);
      float f[8];
      #pragma unroll
      for (int j=0;j<8;++j){
        int o = seg*32 + bq*8 + j;
        float v = bf2f(a8[j]) + bf2f(b8[j]) + de*wdS[o]
                + eav.x*weaS[0][o] + eav.y*weaS[1][o]
                + eav.z*weaS[2][o] + eav.w*weaS[3][o];
        f[j] = siluf(v);
      }
      int4 sv;
      sv.x = (int)cvtpk(f[0],f[1]); sv.y = (int)cvtpk(f[2],f[3]);
      sv.z = (int)cvtpk(f[4],f[5]); sv.w = (int)cvtpk(f[6],f[7]);
      *reinterpret_cast<int4*>(&hidS[el*HST + seg*32 + bq*8]) = sv;
    }
  }
  // gemm64's first loop-top barrier publishes hidS

  f32x4 z = {0.f,0.f,0.f,0.f};
  f32x4 acc2[2][4];
  #pragma unroll
  for (int i=0;i<2;++i){ acc2[i][0]=z; acc2[i][1]=z; acc2[i][2]=z; acc2[i][3]=z; }
  gemm64(hidS, HST, W2p, 4, bkS, acc2, t);
  epilogue_store(acc2, b2, nullptr, hidS, t);     // m_pre (in-place)
  __syncthreads();                                // publish m_pre

  // gate = sigmoid(m_pre . Wg + bg)   (active edges: mask == 1)
  {
    int eg = t >> 2, g = t & 3;
    float p = 0.f;
    #pragma unroll
    for (int bq=0;bq<4;++bq){
      short8v s = *reinterpret_cast<const short8v*>(&hidS[eg*HST + g*32 + bq*8]);
      #pragma unroll
      for (int j=0;j<8;++j) p += bf2f(s[j]) * wgS[g*32 + bq*8 + j];
    }
    p += __shfl_xor(p, 1); p += __shfl_xor(p, 2);
    if (g == 0) scaleS[eg] = sigf(p + bg[0]);
  }
  __syncthreads();                                // publish scaleS

  // magg[col] += m_pre * scale (segmented; cols sorted)
  {
    int o = t & 127, half = t >> 7;
    int ib = half*32;
    float accv = 0.f;
    int curc = colS[ib];
    #pragma unroll 4
    for (int j=0;j<32;++j){
      int i = ib + j;
      int cc = colS[i];
      if (cc != curc){
        atomicAdd(&magg[(size_t)curc*HID + o], accv);
        accv = 0.f; curc = cc;
      }
      accv += bf2f(hidS[i*HST + o]) * scaleS[i];
    }
    atomicAdd(&magg[(size_t)curc*HID + o], accv);
  }

  // hidden2 = silu(scale * (m_pre @ Wc1) + bc1)
  f32x4 acc3[2][4];
  #pragma unroll
  for (int i=0;i<2;++i){ acc3[i][0]=z; acc3[i][1]=z; acc3[i][2]=z; acc3[i][3]=z; }
  gemm64(hidS, HST, C1p, 4, bkS, acc3, t);
  epilogue_store(acc3, bc1, scaleS, hidS, t);     // hidden2 (in-place)
  __syncthreads();                                // publish hidden2

  // cw = hidden2 . Wc2 + cb2
  {
    int eg = t >> 2, g = t & 3;
    float p = 0.f;
    #pragma unroll
    for (int bq=0;bq<4;++bq){
      short8v s = *reinterpret_cast<const short8v*>(&hidS[eg*HST + g*32 + bq*8]);
      #pragma unroll
      for (int j=0;j<8;++j) p += bf2f(s[j]) * wc2S[g*32 + bq*8 + j];
    }
    p += __shfl_xor(p, 1); p += __shfl_xor(p, 2);
    if (g == 0) cwS[eg] = p + cb2[0];
  }
  __syncthreads();                                // publish cwS

  // x_out[col] += coord_diff * cw (segmented)
  if (t < 6){
    int d = t % 3, half = t / 3;
    int ib = half*32;
    float accx = 0.f;
    int curc = colS[ib];
    for (int j=0;j<32;++j){
      int i = ib + j;
      int cc = colS[i];
      if (cc != curc){
        atomicAdd(&xout[curc*3+d], accx);
        accx = 0.f; curc = cc;
      }
      accx += cdS[i][d] * cwS[i];
    }
    atomicAdd(&xout[curc*3+d], accx);
  }
}

// ---- inactive edges: xout[col] += coord_diff * cw_const[l] (8 sorted edges/thread) ----
__global__ void inact_kernel(const int* __restrict__ niT, const int2* __restrict__ rcI,
                             const float* __restrict__ x, const float* __restrict__ cwc,
                             int l, float* __restrict__ xout){
  int Ni = niT[0];
  int base = (blockIdx.x*256 + threadIdx.x)*8;
  if (base >= Ni) return;
  const float cw = cwc[l];
  int end = base + 8; if (end > Ni) end = Ni;
  int curc = rcI[base].y;
  float ax=0.f, ay=0.f, az=0.f;
  for (int i=base;i<end;++i){
    int2 rc = rcI[i];
    if (rc.y != curc){
      atomicAdd(&xout[curc*3+0], ax);
      atomicAdd(&xout[curc*3+1], ay);
      atomicAdd(&xout[curc*3+2], az);
      ax=0.f; ay=0.f; az=0.f; curc = rc.y;
    }
    float dx = x[rc.y*3+0]-x[rc.x*3+0];
    float dy = x[rc.y*3+1]-x[rc.x*3+1];
    float dz = x[rc.y*3+2]-x[rc.x*3+2];
    ax = fmaf(dx,cw,ax); ay = fmaf(dy,cw,ay); az = fmaf(dz,cw,az);
  }
  atomicAdd(&xout[curc*3+0], ax);
  atomicAdd(&xout[curc*3+1], ay);
  atomicAdd(&xout[curc*3+2], az);
}

// ---- fused node MLP + next-layer projections ----
__global__ __launch_bounds__(256) void node2f_kernel(
    float* __restrict__ h, const float* __restrict__ magg,
    const short* __restrict__ W1ap, const short* __restrict__ W1bp,
    const float* __restrict__ bn1,
    const short* __restrict__ Wn2p, const float* __restrict__ bn2,
    const short* __restrict__ Wcp, const float* __restrict__ b1n,
    const short* __restrict__ Wrp,
    short* __restrict__ A, short* __restrict__ B, int doProj)
{
  __shared__ __align__(16) short hT[ME*HST];
  __shared__ __align__(16) short mT[ME*HST];
  __shared__ __align__(16) short bkS[2*4096];
  const int t = threadIdx.x;
  const int n0 = blockIdx.x * ME;
  {
    int nl = t >> 2, seg = t & 3;
    int n = n0 + nl; if (n >= NN) n = NN-1;
    const float4* hp = reinterpret_cast<const float4*>(h + (size_t)n*HID + seg*32);
    const float4* mp = reinterpret_cast<const float4*>(magg + (size_t)n*HID + seg*32);
    #pragma unroll
    for (int bq=0;bq<4;++bq){
      float4 u = hp[bq*2], v = hp[bq*2+1];
      int4 sv;
      sv.x = (int)cvtpk(u.x,u.y); sv.y = (int)cvtpk(u.z,u.w);
      sv.z = (int)cvtpk(v.x,v.y); sv.w = (int)cvtpk(v.z,v.w);
      *reinterpret_cast<int4*>(&hT[nl*HST + seg*32 + bq*8]) = sv;
      float4 u2 = mp[bq*2], v2 = mp[bq*2+1];
      int4 sv2;
      sv2.x = (int)cvtpk(u2.x,u2.y); sv2.y = (int)cvtpk(u2.z,u2.w);
      sv2.z = (int)cvtpk(v2.x,v2.y); sv2.w = (int)cvtpk(v2.z,v2.w);
      *reinterpret_cast<int4*>(&mT[nl*HST + seg*32 + bq*8]) = sv2;
    }
  }
  f32x4 z = {0.f,0.f,0.f,0.f};
  f32x4 acc[2][4];
  #pragma unroll
  for (int i=0;i<2;++i){ acc[i][0]=z; acc[i][1]=z; acc[i][2]=z; acc[i][3]=z; }
  gemm64(hT, HST, W1ap, 4, bkS, acc, t);
  gemm64(mT, HST, W1bp, 4, bkS, acc, t);        // accumulates
  epilogue_store(acc, bn1, nullptr, mT, t);      // silu1 -> mT
  __syncthreads();

  f32x4 acc2[2][4];
  #pragma unroll
  for (int i=0;i<2;++i){ acc2[i][0]=z; acc2[i][1]=z; acc2[i][2]=z; acc2[i][3]=z; }
  gemm64(mT, HST, Wn2p, 4, bkS, acc2, t);

  const int lane = t & 63, w = t >> 6;
  const int q = lane >> 4, fr = lane & 15;
  #pragma unroll
  for (int et=0; et<2; ++et){
    int e0 = (w&1)*32 + et*16 + q*4;
    #pragma unroll
    for (int ot=0; ot<4; ++ot){
      int o = (w>>1)*64 + ot*16 + fr;
      float bv = bn2[o];
      float hn[4];
      #pragma unroll
      for (int r=0;r<4;++r){
        int n = n0 + e0 + r;
        float hv = 0.f;
        if (n < NN){
          size_t idx = (size_t)n*HID + o;
          hv = h[idx] + acc2[et][ot][r] + bv;
          h[idx] = hv;
        }
        hn[r] = hv;
      }
      if (doProj){
        unsigned p01 = cvtpk(hn[0],hn[1]), p23 = cvtpk(hn[2],hn[3]);
        hT[(e0+0)*HST + o] = (short)p01;
        hT[(e0+1)*HST + o] = (short)(p01>>16);
        hT[(e0+2)*HST + o] = (short)p23;
        hT[(e0+3)*HST + o] = (short)(p23>>16);
      }
    }
  }
  if (!doProj) return;
  // (gemm64's loop-top barrier publishes hT)

  f32x4 accA[2][4], accB[2][4];
  #pragma unroll
  for (int i=0;i<2;++i){ accA[i][0]=z;accA[i][1]=z;accA[i][2]=z;accA[i][3]=z;
                         accB[i][0]=z;accB[i][1]=z;accB[i][2]=z;accB[i][3]=z; }
  gemm64(hT, HST, Wcp, 4, bkS, accA, t);
  gemm64(hT, HST, Wrp, 4, bkS, accB, t);
  #pragma unroll
  for (int et=0; et<2; ++et){
    int e0 = (w&1)*32 + et*16 + q*4;
    #pragma unroll
    for (int ot=0; ot<4; ++ot){
      int o = (w>>1)*64 + ot*16 + fr;
      float bv = b1n[o];
      #pragma unroll
      for (int r=0;r<4;++r){
        int n = n0 + e0 + r;
        if (n < NN){
          A[(size_t)n*HID + o] = bfr(accA[et][ot][r] + bv);
          B[(size_t)n*HID + o] = bfr(accB[et][ot][r]);
        }
      }
    }
  }
}

__global__ void pool_kernel(const float* __restrict__ h, const int* __restrict__ batch,
                            float* __restrict__ sums, float* __restrict__ counts){
  int o  = threadIdx.x;
  int n0 = blockIdx.x * 16;
  int curg = batch[n0];
  float accv = 0.f, cnt = 0.f;
  for (int j=0;j<16;++j){
    int n = n0 + j;
    int g = batch[n];
    if (g != curg){
      atomicAdd(&sums[(size_t)curg*HID+o], accv);
      if (o==0) atomicAdd(&counts[curg], cnt);
      accv = 0.f; cnt = 0.f; curg = g;
    }
    accv += h[(size_t)n*HID+o];
    cnt  += 1.f;
  }
  atomicAdd(&sums[(size_t)curg*HID+o], accv);
  if (o==0) atomicAdd(&counts[curg], cnt);
}

__global__ void out_kernel(const float* __restrict__ sums, const float* __restrict__ counts,
                           const float* __restrict__ rW, const float* __restrict__ rb,
                           float* __restrict__ out){
  int g = blockIdx.x; int t = threadIdx.x;
  float v = sums[(size_t)g*HID + t]*rW[t] + sums[(size_t)g*HID + 64 + t]*rW[64+t];
  #pragma unroll
  for (int off=32; off>0; off>>=1) v += __shfl_down(v, off);
  if (t==0) out[g] = v / fmaxf(counts[g], 1.0f) + rb[0];
}

extern "C" void kernel_launch(void* const* d_in, const int* in_sizes, int n_in,
                              void* d_out, int out_size, void* d_ws, size_t ws_size,
                              hipStream_t stream)
{
  const float* x_feat = (const float*)d_in[0];
  const float* pos    = (const float*)d_in[1];
  const float* eattr  = (const float*)d_in[2];
  const float* p      = (const float*)d_in[3];
  const float* embW   = (const float*)d_in[4];
  const float* embB   = (const float*)d_in[5];
  const float* eW1    = (const float*)d_in[6];
  const float* eb1    = (const float*)d_in[7];
  const float* eW2    = (const float*)d_in[8];
  const float* eb2    = (const float*)d_in[9];
  const float* gW     = (const float*)d_in[10];
  const float* gb     = (const float*)d_in[11];
  const float* nW1    = (const float*)d_in[12];
  const float* nb1    = (const float*)d_in[13];
  const float* nW2    = (const float*)d_in[14];
  const float* nb2    = (const float*)d_in[15];
  const float* cW1    = (const float*)d_in[16];
  const float* cb1    = (const float*)d_in[17];
  const float* cW2    = (const float*)d_in[18];
  const float* cb2    = (const float*)d_in[19];
  const float* rW     = (const float*)d_in[20];
  const float* rb     = (const float*)d_in[21];
  const int* eidx     = (const int*)d_in[22];
  const int* einv     = (const int*)d_in[23];
  const int* batch    = (const int*)d_in[24];

  float* ws = (float*)d_ws;
  float* h      = ws;  ws += (size_t)NN*HID;
  float* magg   = ws;  ws += (size_t)(NN+1)*HID;       // +dump row
  float* xA     = ws;  ws += (size_t)(NN+1)*3;         // +dump row
  float* xB     = ws;  ws += (size_t)(NN+1)*3;
  float* sums   = ws;  ws += (size_t)NG*HID;
  float* counts = ws;  ws += NG;
  float* cwc    = ws;  ws += 4;
  int*   histA  = (int*)ws;  ws += NN+1;               // [NN] = Na
  int*   histI  = (int*)ws;  ws += NN+1;               // [NN] = Ni
  int2*  rcA    = (int2*)ws;  ws += (size_t)NE*2;
  int2*  rcI    = (int2*)ws;  ws += (size_t)NE*2;
  float4* eaA   = (float4*)ws; ws += (size_t)NE*4;
  short* Abuf = (short*)ws;  ws += (size_t)(NN+1)*HID/2;   // +dump row
  short* Bbuf = (short*)ws;  ws += (size_t)(NN+1)*HID/2;
  const size_t PK = (size_t)NL*4*4*HID*8;   // shorts per packed array
  short* W1cp  = (short*)ws;
  short* W1rp  = W1cp  + PK;
  short* W2p   = W1rp  + PK;
  short* C1p   = W2p   + PK;
  short* Wn1ap = C1p   + PK;
  short* Wn1bp = Wn1ap + PK;
  short* Wn2p  = Wn1bp + PK;

  // partitioned counting sort by col: active (mask=1) and inactive streams
  hipMemsetAsync(histA, 0, sizeof(int)*2*(NN+1), stream);
  hist2_kernel<<<(NE+255)/256, 256, 0, stream>>>(eidx, p, einv, histA, histI);
  scan_kernel<<<1, 1024, 0, stream>>>(histA);
  scan_kernel<<<1, 1024, 0, stream>>>(histI);
  scatter2_kernel<<<(NE+255)/256, 256, 0, stream>>>(eidx, p, einv, eattr,
                                                    histA, histI, rcA, eaA, rcI);
  pad_kernel<<<1, 64, 0, stream>>>(histA + NN, rcA, eaA);
  cwc_kernel<<<NL, 128, 0, stream>>>(cb1, cW2, cb2, cwc);

  // prepack bf16 weights (each [L][4][4][128][8])
  const int PG = (int)((PK + 255)/256);
  prepack_kernel<<<PG, 256, 0, stream>>>(eW1, W1cp, 261, 0);
  prepack_kernel<<<PG, 256, 0, stream>>>(eW1, W1rp, 261, 128);
  prepack_kernel<<<PG, 256, 0, stream>>>(eW2, W2p, 128, 0);
  prepack_kernel<<<PG, 256, 0, stream>>>(cW1, C1p, 128, 0);
  prepack_kernel<<<PG, 256, 0, stream>>>(nW1, Wn1ap, 256, 0);
  prepack_kernel<<<PG, 256, 0, stream>>>(nW1, Wn1bp, 256, 128);
  prepack_kernel<<<PG, 256, 0, stream>>>(nW2, Wn2p, 128, 0);

  hipMemcpyAsync(xA, pos, sizeof(float)*NN*3, hipMemcpyDeviceToDevice, stream);
  embed_kernel<<<NN, HID, 0, stream>>>(x_feat, embW, embB, h);
  // layer-0 projections
  nodeproj_kernel<<<NPB, 256, 0, stream>>>(h, W1cp, eb1, W1rp, Abuf, Bbuf);

  float* xc = xA; float* xn = xB;
  for (int l=0;l<NL;++l){
    const size_t wofs = (size_t)l*4*4096;
    const size_t wofsn = (size_t)(l+1)*4*4096;
    hipMemsetAsync(magg, 0, sizeof(float)*(size_t)NN*HID, stream);
    hipMemcpyAsync(xn, xc, sizeof(float)*NN*3, hipMemcpyDeviceToDevice, stream);
    edge2_kernel<<<NWG, 256, 0, stream>>>(Abuf, Bbuf, xc, rcA, eaA, histA + NN,
        eW1 + (size_t)l*261*HID,
        W2p + wofs, eb2 + l*HID,
        gW  + l*HID, gb + l,
        C1p + wofs, cb1 + l*HID,
        cW2 + l*HID, cb2 + l,
        magg, xn);
    inact_kernel<<<NIB, 256, 0, stream>>>(histI + NN, rcI, xc, cwc, l, xn);
    int doProj = (l+1 < NL);
    node2f_kernel<<<NPB, 256, 0, stream>>>(h, magg,
        Wn1ap + wofs, Wn1bp + wofs, nb1 + l*HID,
        Wn2p + wofs, nb2 + l*HID,
        W1cp + (doProj?wofsn:0), eb1 + (doProj?(l+1)*HID:0),
        W1rp + (doProj?wofsn:0),
        Abuf, Bbuf, doProj);
    float* tmp = xc; xc = xn; xn = tmp;
  }
  hipMemsetAsync(sums, 0, sizeof(float)*((size_t)NG*HID + NG), stream);
  pool_kernel<<<NN/16, HID, 0, stream>>>(h, batch, sums, counts);
  out_kernel<<<NG, 64, 0, stream>>>(sums, counts, rW, rb, (float*)d_out);
}

// Round 14
// 1127.040 us; speedup vs baseline: 1.5183x; 1.0928x over previous
//
#include <hip/hip_runtime.h>

#define NN 50000
#define NE 800000
#define HID 128
#define NG 2500
#define NL 4
#define ME 64       // edges (or nodes) per block
#define HST 136     // LDS tile row stride (shorts): 272B, bank-phase 4 -> 2-way max (free)
#define NPB 782     // node blocks: ceil(50000/64)
#define NWG (NE/ME) // 12500 max edge blocks (device-side early exit past active count)
#define NIB 391     // inactive-edge blocks: ceil(NE/8/256)
#define PKC 65536   // shorts per packed weight array: NL*4*4*HID*8

typedef __attribute__((ext_vector_type(8))) short short8v;
typedef __attribute__((ext_vector_type(4))) float f32x4;

__device__ __forceinline__ float sigf(float x){ return 1.0f/(1.0f+__expf(-x)); }
__device__ __forceinline__ float siluf(float x){ return x/(1.0f+__expf(-x)); }
__device__ __forceinline__ short bfr(float x){           // scalar f32->bf16 (RNE)
  unsigned u = __float_as_uint(x);
  u += 0x7fffu + ((u>>16)&1u);
  return (short)(u>>16);
}
__device__ __forceinline__ unsigned cvtpk(float lo, float hi){
  unsigned r;
  asm("v_cvt_pk_bf16_f32 %0, %1, %2" : "=v"(r) : "v"(lo), "v"(hi));
  return r;
}
__device__ __forceinline__ float bf2f(short s){
  return __uint_as_float(((unsigned)(unsigned short)s)<<16);
}

// ------------- partitioned counting sort of edges by col (active = mask 1) -------------
__global__ void hist2_kernel(const int* __restrict__ eidx, const float* __restrict__ p,
                             const int* __restrict__ inv,
                             int* __restrict__ histA, int* __restrict__ histI){
  int e = blockIdx.x*256 + threadIdx.x;
  if (e < NE){
    int c = eidx[NE+e];
    if (p[inv[e]] >= 0.0f) atomicAdd(&histA[c], 1);
    else                   atomicAdd(&histI[c], 1);
  }
}
// in-place exclusive scans over NN entries (block 0: histA, block 1: histI); total -> [NN]
__global__ __launch_bounds__(1024) void scan2_kernel(int* __restrict__ hA,
                                                     int* __restrict__ hI){
  int* cursor = blockIdx.x ? hI : hA;
  __shared__ int part[1024];
  int t = threadIdx.x;
  const int CH = (NN + 1023)/1024;
  int base = t*CH;
  int s = 0;
  for (int j=0;j<CH;++j){ int i=base+j; if (i<NN) s += cursor[i]; }
  part[t] = s; __syncthreads();
  for (int d=1; d<1024; d<<=1){
    int v = (t>=d) ? part[t-d] : 0;
    __syncthreads();
    part[t] += v;
    __syncthreads();
  }
  int ex = (t==0) ? 0 : part[t-1];
  for (int j=0;j<CH;++j){
    int i=base+j;
    if (i<NN){ int hv = cursor[i]; cursor[i] = ex; ex += hv; }
  }
  if (t == 1023) cursor[NN] = part[1023];   // total
}
// fused scatter + stream materialization into active / inactive sorted streams
__global__ void scatter2_kernel(const int* __restrict__ eidx, const float* __restrict__ p,
                                const int* __restrict__ inv, const float* __restrict__ ea,
                                int* __restrict__ curA, int* __restrict__ curI,
                                int2* __restrict__ rcA, float4* __restrict__ eaA,
                                int2* __restrict__ rcI){
  int e = blockIdx.x*256 + threadIdx.x;
  if (e >= NE) return;
  int r = eidx[e], c = eidx[NE+e];
  int2 rc; rc.x = r; rc.y = c;
  if (p[inv[e]] >= 0.0f){
    int pos = atomicAdd(&curA[c], 1);
    rcA[pos] = rc;
    eaA[pos] = *reinterpret_cast<const float4*>(ea + (size_t)e*4);
  } else {
    int pos = atomicAdd(&curI[c], 1);
    rcI[pos] = rc;
  }
}
// pad active stream to a multiple of 64 with dummy edges pointing at dump row NN
__global__ void pad_kernel(const int* __restrict__ naT, int2* __restrict__ rcA,
                           float4* __restrict__ eaA){
  int Na = naT[0];
  int NaP = (Na + 63) & ~63;
  int i = Na + threadIdx.x;
  if (i < NaP){
    int2 rc; rc.x = 0; rc.y = NN;   // row 0 (valid), col NN (dump row)
    rcA[i] = rc;
    float4 zz; zz.x=0.f; zz.y=0.f; zz.z=0.f; zz.w=0.f;
    eaA[i] = zz;
  }
}
// per-layer constant cw for masked edges: silu(bc1) . Wc2 + cb2 (f32 exact)
__global__ void cwc_kernel(const float* __restrict__ cb1, const float* __restrict__ cW2,
                           const float* __restrict__ cb2, float* __restrict__ cwc){
  int l = blockIdx.x, o = threadIdx.x;   // 128 threads
  float v = siluf(cb1[l*HID+o]) * cW2[l*HID+o];
  #pragma unroll
  for (int off=32; off>0; off>>=1) v += __shfl_down(v, off);
  __shared__ float red[2];
  if ((o & 63) == 0) red[o>>6] = v;
  __syncthreads();
  if (o == 0) cwc[l] = red[0] + red[1] + cb2[l];
}

// ---- single-launch weight prepack: 7 regions, dst contiguous at stride PKC ----
// region r: rows [roff,roff+128) of [L][Ktot][128] -> [L][ks4][q4][o128][kk8] bf16
__global__ void prepack_all(const float* __restrict__ eW1, const float* __restrict__ eW2,
                            const float* __restrict__ cW1, const float* __restrict__ nW1,
                            const float* __restrict__ nW2, short* __restrict__ dst0){
  int region = blockIdx.x >> 8;                       // PKC/256 = 256 blocks per region
  int idx = ((blockIdx.x & 255) << 8) + threadIdx.x;
  const float* W; int Ktot, roff;
  switch(region){
    case 0: W=eW1; Ktot=261; roff=0;   break;
    case 1: W=eW1; Ktot=261; roff=128; break;
    case 2: W=eW2; Ktot=128; roff=0;   break;
    case 3: W=cW1; Ktot=128; roff=0;   break;
    case 4: W=nW1; Ktot=256; roff=0;   break;
    case 5: W=nW1; Ktot=256; roff=128; break;
    default: W=nW2; Ktot=128; roff=0;  break;
  }
  int kk8 = idx & 7;
  int o   = (idx>>3) & 127;
  int q   = (idx>>10) & 3;
  int ks  = (idx>>12) & 3;
  int l   = idx >> 14;
  int k = roff + ks*32 + q*8 + kk8;
  float v = (k < Ktot) ? W[((size_t)l*Ktot + k)*HID + o] : 0.0f;
  dst0[(size_t)region*PKC + idx] = bfr(v);
}

// ---------------- MFMA tile-GEMM: [64 x 128] (LDS bf16) @ [128 x 128] (prepacked) ----
__device__ __forceinline__ void gemm64(const short* As, int astride,
                                       const short* Wp, int nks,
                                       short* bkS, f32x4 acc[2][4], int t)
{
  const int lane = t & 63, w = t >> 6;
  const int q = lane >> 4, fr = lane & 15;
  const int erow = (w & 1) * 32;
  const int ocol = (w >> 1) * 64;
  const int4* g = reinterpret_cast<const int4*>(Wp);
  int4* bkw = reinterpret_cast<int4*>(bkS);
  int4 p0 = g[t], p1 = g[256 + t];
  for (int ks = 0; ks < nks; ++ks){
    const int buf = (ks & 1) * 512;            // int4 units (4096 shorts)
    bkw[buf + t] = p0; bkw[buf + 256 + t] = p1;
    __syncthreads();
    if (ks + 1 < nks){ p0 = g[(ks+1)*512 + t]; p1 = g[(ks+1)*512 + 256 + t]; }
    const short* bb = bkS + buf*8 + q*1024;
    short8v a[2], b[4];
    #pragma unroll
    for (int et=0; et<2; ++et)
      a[et] = *reinterpret_cast<const short8v*>(As + (erow + et*16 + fr)*astride + ks*32 + q*8);
    #pragma unroll
    for (int ot=0; ot<4; ++ot)
      b[ot] = *reinterpret_cast<const short8v*>(bb + (ocol + ot*16 + fr)*8);
    #pragma unroll
    for (int et=0; et<2; ++et)
      #pragma unroll
      for (int ot=0; ot<4; ++ot)
        acc[et][ot] = __builtin_amdgcn_mfma_f32_16x16x32_bf16(a[et], b[ot], acc[et][ot], 0, 0, 0);
  }
  __syncthreads();
}

// acc -> silu(scale*acc + bias) -> bf16 LDS tile [64][HST]; scaleS==nullptr -> scale=1
__device__ __forceinline__ void epilogue_store(const f32x4 acc[2][4],
                                               const float* __restrict__ bias,
                                               const float* __restrict__ scaleS,
                                               short* dst, int t)
{
  const int lane = t & 63, w = t >> 6;
  const int q = lane >> 4, fr = lane & 15;
  #pragma unroll
  for (int et=0; et<2; ++et){
    const int e0 = (w&1)*32 + et*16 + q*4;
    float s0=1.f,s1=1.f,s2=1.f,s3=1.f;
    if (scaleS){ s0=scaleS[e0]; s1=scaleS[e0+1]; s2=scaleS[e0+2]; s3=scaleS[e0+3]; }
    #pragma unroll
    for (int ot=0; ot<4; ++ot){
      int o = (w>>1)*64 + ot*16 + fr;
      float bv = bias[o];
      unsigned p01 = cvtpk(siluf(fmaf(s0,acc[et][ot][0],bv)), siluf(fmaf(s1,acc[et][ot][1],bv)));
      unsigned p23 = cvtpk(siluf(fmaf(s2,acc[et][ot][2],bv)), siluf(fmaf(s3,acc[et][ot][3],bv)));
      dst[(e0+0)*HST + o] = (short)p01;
      dst[(e0+1)*HST + o] = (short)(p01>>16);
      dst[(e0+2)*HST + o] = (short)p23;
      dst[(e0+3)*HST + o] = (short)(p23>>16);
    }
  }
}

// ---- fused embed + layer-0 node projections ----
// h = x_feat@embW + embB (f32, written once); A = bf16(h@W1hc + b1), B = bf16(h@W1hr)
__global__ __launch_bounds__(256) void embproj_kernel(
    const float* __restrict__ xf, const float* __restrict__ embW,
    const float* __restrict__ embB,
    const short* __restrict__ Wcp, const float* __restrict__ b1,
    const short* __restrict__ Wrp,
    float* __restrict__ h, short* __restrict__ A, short* __restrict__ B)
{
  __shared__ __align__(16) short hT[ME*HST];
  __shared__ __align__(16) short bkS[2*4096];
  __shared__ float xfS[ME][12];
  __shared__ float wS[11][HID];
  __shared__ float bS[HID];
  const int t = threadIdx.x;
  const int n0 = blockIdx.x * ME;
  for (int i = t; i < ME*11; i += 256){
    int nl = i / 11, ii = i % 11;
    int n = n0 + nl; if (n >= NN) n = NN-1;
    xfS[nl][ii] = xf[(size_t)n*11 + ii];
  }
  for (int i = t; i < 11*HID; i += 256) wS[i>>7][i&127] = embW[i];
  if (t < HID) bS[t] = embB[t];
  __syncthreads();
  {
    int nl = t >> 2, seg = t & 3;
    int n = n0 + nl;
    float hv[32];
    #pragma unroll
    for (int j=0;j<32;++j){
      int o = seg*32 + j;
      float s = bS[o];
      #pragma unroll
      for (int i=0;i<11;++i) s = fmaf(xfS[nl][i], wS[i][o], s);
      hv[j] = s;
    }
    if (n < NN){
      float4* hp = reinterpret_cast<float4*>(h + (size_t)n*HID + seg*32);
      #pragma unroll
      for (int j=0;j<8;++j){
        float4 u; u.x=hv[j*4]; u.y=hv[j*4+1]; u.z=hv[j*4+2]; u.w=hv[j*4+3];
        hp[j] = u;
      }
    }
    #pragma unroll
    for (int bq=0;bq<4;++bq){
      int4 sv;
      sv.x = (int)cvtpk(hv[bq*8+0],hv[bq*8+1]); sv.y = (int)cvtpk(hv[bq*8+2],hv[bq*8+3]);
      sv.z = (int)cvtpk(hv[bq*8+4],hv[bq*8+5]); sv.w = (int)cvtpk(hv[bq*8+6],hv[bq*8+7]);
      *reinterpret_cast<int4*>(&hT[nl*HST + seg*32 + bq*8]) = sv;
    }
  }
  // gemm64's first loop-top barrier publishes hT
  f32x4 z = {0.f,0.f,0.f,0.f};
  f32x4 accA[2][4], accB[2][4];
  #pragma unroll
  for (int i=0;i<2;++i){ accA[i][0]=z;accA[i][1]=z;accA[i][2]=z;accA[i][3]=z;
                         accB[i][0]=z;accB[i][1]=z;accB[i][2]=z;accB[i][3]=z; }
  gemm64(hT, HST, Wcp, 4, bkS, accA, t);
  gemm64(hT, HST, Wrp, 4, bkS, accB, t);
  const int lane = t & 63, w = t >> 6;
  const int q = lane >> 4, fr = lane & 15;
  #pragma unroll
  for (int et=0; et<2; ++et){
    int e0 = (w&1)*32 + et*16 + q*4;
    #pragma unroll
    for (int ot=0; ot<4; ++ot){
      int o = (w>>1)*64 + ot*16 + fr;
      float bv = b1[o];
      #pragma unroll
      for (int r=0;r<4;++r){
        int n = n0 + e0 + r;
        if (n < NN){
          A[(size_t)n*HID + o] = bfr(accA[et][ot][r] + bv);
          B[(size_t)n*HID + o] = bfr(accB[et][ot][r]);
        }
      }
    }
  }
}

// ---------------- edge kernel (ACTIVE edges only; dynamic-range XCD swizzle) ----------------
__global__ __launch_bounds__(256) void edge2_kernel(
    const short* __restrict__ A, const short* __restrict__ B,
    const float* __restrict__ x,
    const int2* __restrict__ rcS, const float4* __restrict__ eaS,
    const int* __restrict__ naT,
    const float* __restrict__ wrow,   // eW1 + l*261*128 : rows 256..260 = wd, wea
    const short* __restrict__ W2p, const float* __restrict__ b2,
    const float* __restrict__ Wg, const float* __restrict__ bg,
    const short* __restrict__ C1p, const float* __restrict__ bc1,
    const float* __restrict__ Wc2, const float* __restrict__ cb2,
    float* __restrict__ magg, float* __restrict__ xout)
{
  __shared__ __align__(16) short hidS[ME*HST];   // hidden1 -> m_pre (kept) -> hidden2
  __shared__ __align__(16) short bkS[2*4096];
  __shared__ float wdS[HID], wgS[HID], wc2S[HID];
  __shared__ float weaS[4][HID];
  __shared__ float scaleS[ME], cwS[ME], distS[ME], cdS[ME][3];
  __shared__ int colS[ME];

  const int t = threadIdx.x;
  // dynamic-range bijective XCD swizzle: spread ACTIVE blocks across all XCDs
  const int nab = (naT[0] + 63) >> 6;            // number of active blocks
  if ((int)blockIdx.x >= nab) return;
  const int qq = nab >> 3, rr = nab & 7;
  const int xcd = blockIdx.x & 7, sub = blockIdx.x >> 3;
  const int bid = (xcd < rr ? xcd*(qq+1) : rr*(qq+1) + (xcd-rr)*qq) + sub;
  const int i0 = bid * ME;

  // issue per-thread gathers early (4 threads/edge, 32 channels each)
  const int el = t >> 2, seg = t & 3;
  const int2 rc = rcS[i0 + el];
  const int4* Ap = reinterpret_cast<const int4*>(A + (size_t)rc.y*HID + seg*32);
  const int4* Bp = reinterpret_cast<const int4*>(B + (size_t)rc.x*HID + seg*32);
  int4 av0=Ap[0], av1=Ap[1], av2=Ap[2], av3=Ap[3];
  int4 bv0=Bp[0], bv1=Bp[1], bv2=Bp[2], bv3=Bp[3];
  float4 eav = eaS[i0 + el];

  if (t < HID){
    wdS[t] = wrow[256*HID + t];
    wgS[t] = Wg[t]; wc2S[t] = Wc2[t];
    #pragma unroll
    for (int j=0;j<4;++j) weaS[j][t] = wrow[(257+j)*HID + t];
  }
  if (t < ME){
    int2 rc2 = rcS[i0 + t];
    colS[t] = rc2.y;
    float dx = x[rc2.y*3+0]-x[rc2.x*3+0];
    float dy = x[rc2.y*3+1]-x[rc2.x*3+1];
    float dz = x[rc2.y*3+2]-x[rc2.x*3+2];
    cdS[t][0]=dx; cdS[t][1]=dy; cdS[t][2]=dz;
    distS[t] = sqrtf(dx*dx+dy*dy+dz*dz);
  }
  __syncthreads();

  // hidden1 = silu(A[col] + B[row] + dist*wd + ea@wea)
  {
    float de = distS[el];
    const int4 avs[4] = {av0,av1,av2,av3};
    const int4 bvs[4] = {bv0,bv1,bv2,bv3};
    #pragma unroll
    for (int bq=0;bq<4;++bq){
      short8v a8 = *reinterpret_cast<const short8v*>(&avs[bq]);
      short8v b8 = *reinterpret_cast<const short8v*>(&bvs[bq]);
      float f[8];
      #pragma unroll
      for (int j=0;j<8;++j){
        int o = seg*32 + bq*8 + j;
        float v = bf2f(a8[j]) + bf2f(b8[j]) + de*wdS[o]
                + eav.x*weaS[0][o] + eav.y*weaS[1][o]
                + eav.z*weaS[2][o] + eav.w*weaS[3][o];
        f[j] = siluf(v);
      }
      int4 sv;
      sv.x = (int)cvtpk(f[0],f[1]); sv.y = (int)cvtpk(f[2],f[3]);
      sv.z = (int)cvtpk(f[4],f[5]); sv.w = (int)cvtpk(f[6],f[7]);
      *reinterpret_cast<int4*>(&hidS[el*HST + seg*32 + bq*8]) = sv;
    }
  }
  // gemm64's first loop-top barrier publishes hidS

  f32x4 z = {0.f,0.f,0.f,0.f};
  f32x4 acc2[2][4];
  #pragma unroll
  for (int i=0;i<2;++i){ acc2[i][0]=z; acc2[i][1]=z; acc2[i][2]=z; acc2[i][3]=z; }
  gemm64(hidS, HST, W2p, 4, bkS, acc2, t);
  epilogue_store(acc2, b2, nullptr, hidS, t);     // m_pre (in-place)
  __syncthreads();                                // publish m_pre

  // gate = sigmoid(m_pre . Wg + bg)   (active edges: mask == 1)
  {
    int eg = t >> 2, g = t & 3;
    float p = 0.f;
    #pragma unroll
    for (int bq=0;bq<4;++bq){
      short8v s = *reinterpret_cast<const short8v*>(&hidS[eg*HST + g*32 + bq*8]);
      #pragma unroll
      for (int j=0;j<8;++j) p += bf2f(s[j]) * wgS[g*32 + bq*8 + j];
    }
    p += __shfl_xor(p, 1); p += __shfl_xor(p, 2);
    if (g == 0) scaleS[eg] = sigf(p + bg[0]);
  }
  __syncthreads();                                // publish scaleS

  // magg[col] += m_pre * scale (segmented; cols sorted)
  {
    int o = t & 127, half = t >> 7;
    int ib = half*32;
    float accv = 0.f;
    int curc = colS[ib];
    #pragma unroll 4
    for (int j=0;j<32;++j){
      int i = ib + j;
      int cc = colS[i];
      if (cc != curc){
        atomicAdd(&magg[(size_t)curc*HID + o], accv);
        accv = 0.f; curc = cc;
      }
      accv += bf2f(hidS[i*HST + o]) * scaleS[i];
    }
    atomicAdd(&magg[(size_t)curc*HID + o], accv);
  }

  // hidden2 = silu(scale * (m_pre @ Wc1) + bc1)
  f32x4 acc3[2][4];
  #pragma unroll
  for (int i=0;i<2;++i){ acc3[i][0]=z; acc3[i][1]=z; acc3[i][2]=z; acc3[i][3]=z; }
  gemm64(hidS, HST, C1p, 4, bkS, acc3, t);
  epilogue_store(acc3, bc1, scaleS, hidS, t);     // hidden2 (in-place)
  __syncthreads();                                // publish hidden2

  // cw = hidden2 . Wc2 + cb2
  {
    int eg = t >> 2, g = t & 3;
    float p = 0.f;
    #pragma unroll
    for (int bq=0;bq<4;++bq){
      short8v s = *reinterpret_cast<const short8v*>(&hidS[eg*HST + g*32 + bq*8]);
      #pragma unroll
      for (int j=0;j<8;++j) p += bf2f(s[j]) * wc2S[g*32 + bq*8 + j];
    }
    p += __shfl_xor(p, 1); p += __shfl_xor(p, 2);
    if (g == 0) cwS[eg] = p + cb2[0];
  }
  __syncthreads();                                // publish cwS

  // x_out[col] += coord_diff * cw (segmented)
  if (t < 6){
    int d = t % 3, half = t / 3;
    int ib = half*32;
    float accx = 0.f;
    int curc = colS[ib];
    for (int j=0;j<32;++j){
      int i = ib + j;
      int cc = colS[i];
      if (cc != curc){
        atomicAdd(&xout[curc*3+d], accx);
        accx = 0.f; curc = cc;
      }
      accx += cdS[i][d] * cwS[i];
    }
    atomicAdd(&xout[curc*3+d], accx);
  }
}

// ---- inactive edges: xout[col] += coord_diff * cw_const[l] (8 sorted edges/thread) ----
__global__ void inact_kernel(const int* __restrict__ niT, const int2* __restrict__ rcI,
                             const float* __restrict__ x, const float* __restrict__ cwc,
                             int l, float* __restrict__ xout){
  int Ni = niT[0];
  int base = (blockIdx.x*256 + threadIdx.x)*8;
  if (base >= Ni) return;
  const float cw = cwc[l];
  int end = base + 8; if (end > Ni) end = Ni;
  int curc = rcI[base].y;
  float ax=0.f, ay=0.f, az=0.f;
  for (int i=base;i<end;++i){
    int2 rc = rcI[i];
    if (rc.y != curc){
      atomicAdd(&xout[curc*3+0], ax);
      atomicAdd(&xout[curc*3+1], ay);
      atomicAdd(&xout[curc*3+2], az);
      ax=0.f; ay=0.f; az=0.f; curc = rc.y;
    }
    float dx = x[rc.y*3+0]-x[rc.x*3+0];
    float dy = x[rc.y*3+1]-x[rc.x*3+1];
    float dz = x[rc.y*3+2]-x[rc.x*3+2];
    ax = fmaf(dx,cw,ax); ay = fmaf(dy,cw,ay); az = fmaf(dz,cw,az);
  }
  atomicAdd(&xout[curc*3+0], ax);
  atomicAdd(&xout[curc*3+1], ay);
  atomicAdd(&xout[curc*3+2], az);
}

// ---- fused node MLP + next-layer projections ----
__global__ __launch_bounds__(256) void node2f_kernel(
    float* __restrict__ h, const float* __restrict__ magg,
    const short* __restrict__ W1ap, const short* __restrict__ W1bp,
    const float* __restrict__ bn1,
    const short* __restrict__ Wn2p, const float* __restrict__ bn2,
    const short* __restrict__ Wcp, const float* __restrict__ b1n,
    const short* __restrict__ Wrp,
    short* __restrict__ A, short* __restrict__ B, int doProj)
{
  __shared__ __align__(16) short hT[ME*HST];
  __shared__ __align__(16) short mT[ME*HST];
  __shared__ __align__(16) short bkS[2*4096];
  const int t = threadIdx.x;
  const int n0 = blockIdx.x * ME;
  {
    int nl = t >> 2, seg = t & 3;
    int n = n0 + nl; if (n >= NN) n = NN-1;
    const float4* hp = reinterpret_cast<const float4*>(h + (size_t)n*HID + seg*32);
    const float4* mp = reinterpret_cast<const float4*>(magg + (size_t)n*HID + seg*32);
    #pragma unroll
    for (int bq=0;bq<4;++bq){
      float4 u = hp[bq*2], v = hp[bq*2+1];
      int4 sv;
      sv.x = (int)cvtpk(u.x,u.y); sv.y = (int)cvtpk(u.z,u.w);
      sv.z = (int)cvtpk(v.x,v.y); sv.w = (int)cvtpk(v.z,v.w);
      *reinterpret_cast<int4*>(&hT[nl*HST + seg*32 + bq*8]) = sv;
      float4 u2 = mp[bq*2], v2 = mp[bq*2+1];
      int4 sv2;
      sv2.x = (int)cvtpk(u2.x,u2.y); sv2.y = (int)cvtpk(u2.z,u2.w);
      sv2.z = (int)cvtpk(v2.x,v2.y); sv2.w = (int)cvtpk(v2.z,v2.w);
      *reinterpret_cast<int4*>(&mT[nl*HST + seg*32 + bq*8]) = sv2;
    }
  }
  f32x4 z = {0.f,0.f,0.f,0.f};
  f32x4 acc[2][4];
  #pragma unroll
  for (int i=0;i<2;++i){ acc[i][0]=z; acc[i][1]=z; acc[i][2]=z; acc[i][3]=z; }
  gemm64(hT, HST, W1ap, 4, bkS, acc, t);
  gemm64(mT, HST, W1bp, 4, bkS, acc, t);        // accumulates
  epilogue_store(acc, bn1, nullptr, mT, t);      // silu1 -> mT
  __syncthreads();

  f32x4 acc2[2][4];
  #pragma unroll
  for (int i=0;i<2;++i){ acc2[i][0]=z; acc2[i][1]=z; acc2[i][2]=z; acc2[i][3]=z; }
  gemm64(mT, HST, Wn2p, 4, bkS, acc2, t);

  const int lane = t & 63, w = t >> 6;
  const int q = lane >> 4, fr = lane & 15;
  #pragma unroll
  for (int et=0; et<2; ++et){
    int e0 = (w&1)*32 + et*16 + q*4;
    #pragma unroll
    for (int ot=0; ot<4; ++ot){
      int o = (w>>1)*64 + ot*16 + fr;
      float bv = bn2[o];
      float hn[4];
      #pragma unroll
      for (int r=0;r<4;++r){
        int n = n0 + e0 + r;
        float hv = 0.f;
        if (n < NN){
          size_t idx = (size_t)n*HID + o;
          hv = h[idx] + acc2[et][ot][r] + bv;
          h[idx] = hv;
        }
        hn[r] = hv;
      }
      if (doProj){
        unsigned p01 = cvtpk(hn[0],hn[1]), p23 = cvtpk(hn[2],hn[3]);
        hT[(e0+0)*HST + o] = (short)p01;
        hT[(e0+1)*HST + o] = (short)(p01>>16);
        hT[(e0+2)*HST + o] = (short)p23;
        hT[(e0+3)*HST + o] = (short)(p23>>16);
      }
    }
  }
  if (!doProj) return;
  // (gemm64's loop-top barrier publishes hT)

  f32x4 accA[2][4], accB[2][4];
  #pragma unroll
  for (int i=0;i<2;++i){ accA[i][0]=z;accA[i][1]=z;accA[i][2]=z;accA[i][3]=z;
                         accB[i][0]=z;accB[i][1]=z;accB[i][2]=z;accB[i][3]=z; }
  gemm64(hT, HST, Wcp, 4, bkS, accA, t);
  gemm64(hT, HST, Wrp, 4, bkS, accB, t);
  #pragma unroll
  for (int et=0; et<2; ++et){
    int e0 = (w&1)*32 + et*16 + q*4;
    #pragma unroll
    for (int ot=0; ot<4; ++ot){
      int o = (w>>1)*64 + ot*16 + fr;
      float bv = b1n[o];
      #pragma unroll
      for (int r=0;r<4;++r){
        int n = n0 + e0 + r;
        if (n < NN){
          A[(size_t)n*HID + o] = bfr(accA[et][ot][r] + bv);
          B[(size_t)n*HID + o] = bfr(accB[et][ot][r]);
        }
      }
    }
  }
}

__global__ void pool_kernel(const float* __restrict__ h, const int* __restrict__ batch,
                            float* __restrict__ sums, float* __restrict__ counts){
  int o  = threadIdx.x;
  int n0 = blockIdx.x * 16;
  int curg = batch[n0];
  float accv = 0.f, cnt = 0.f;
  for (int j=0;j<16;++j){
    int n = n0 + j;
    int g = batch[n];
    if (g != curg){
      atomicAdd(&sums[(size_t)curg*HID+o], accv);
      if (o==0) atomicAdd(&counts[curg], cnt);
      accv = 0.f; cnt = 0.f; curg = g;
    }
    accv += h[(size_t)n*HID+o];
    cnt  += 1.f;
  }
  atomicAdd(&sums[(size_t)curg*HID+o], accv);
  if (o==0) atomicAdd(&counts[curg], cnt);
}

__global__ void out_kernel(const float* __restrict__ sums, const float* __restrict__ counts,
                           const float* __restrict__ rW, const float* __restrict__ rb,
                           float* __restrict__ out){
  int g = blockIdx.x; int t = threadIdx.x;
  float v = sums[(size_t)g*HID + t]*rW[t] + sums[(size_t)g*HID + 64 + t]*rW[64+t];
  #pragma unroll
  for (int off=32; off>0; off>>=1) v += __shfl_down(v, off);
  if (t==0) out[g] = v / fmaxf(counts[g], 1.0f) + rb[0];
}

extern "C" void kernel_launch(void* const* d_in, const int* in_sizes, int n_in,
                              void* d_out, int out_size, void* d_ws, size_t ws_size,
                              hipStream_t stream)
{
  const float* x_feat = (const float*)d_in[0];
  const float* pos    = (const float*)d_in[1];
  const float* eattr  = (const float*)d_in[2];
  const float* p      = (const float*)d_in[3];
  const float* embW   = (const float*)d_in[4];
  const float* embB   = (const float*)d_in[5];
  const float* eW1    = (const float*)d_in[6];
  const float* eb1    = (const float*)d_in[7];
  const float* eW2    = (const float*)d_in[8];
  const float* eb2    = (const float*)d_in[9];
  const float* gW     = (const float*)d_in[10];
  const float* gb     = (const float*)d_in[11];
  const float* nW1    = (const float*)d_in[12];
  const float* nb1    = (const float*)d_in[13];
  const float* nW2    = (const float*)d_in[14];
  const float* nb2    = (const float*)d_in[15];
  const float* cW1    = (const float*)d_in[16];
  const float* cb1    = (const float*)d_in[17];
  const float* cW2    = (const float*)d_in[18];
  const float* cb2    = (const float*)d_in[19];
  const float* rW     = (const float*)d_in[20];
  const float* rb     = (const float*)d_in[21];
  const int* eidx     = (const int*)d_in[22];
  const int* einv     = (const int*)d_in[23];
  const int* batch    = (const int*)d_in[24];

  float* ws = (float*)d_ws;
  float* h      = ws;  ws += (size_t)NN*HID;
  float* magg   = ws;  ws += (size_t)(NN+1)*HID;       // +dump row
  float* xA     = ws;  ws += (size_t)(NN+1)*3;         // +dump row
  float* xB     = ws;  ws += (size_t)(NN+1)*3;
  float* sums   = ws;  ws += (size_t)NG*HID;
  float* counts = ws;  ws += NG;
  float* cwc    = ws;  ws += 4;
  int*   histA  = (int*)ws;  ws += NN+1;               // [NN] = Na
  int*   histI  = (int*)ws;  ws += NN+1;               // [NN] = Ni
  int2*  rcA    = (int2*)ws;  ws += (size_t)NE*2;
  int2*  rcI    = (int2*)ws;  ws += (size_t)NE*2;
  float4* eaA   = (float4*)ws; ws += (size_t)NE*4;
  short* Abuf = (short*)ws;  ws += (size_t)(NN+1)*HID/2;   // +dump row
  short* Bbuf = (short*)ws;  ws += (size_t)(NN+1)*HID/2;
  short* W1cp  = (short*)ws;                           // 7 contiguous arrays, stride PKC
  short* W1rp  = W1cp  + PKC;
  short* W2p   = W1rp  + PKC;
  short* C1p   = W2p   + PKC;
  short* Wn1ap = C1p   + PKC;
  short* Wn1bp = Wn1ap + PKC;
  short* Wn2p  = Wn1bp + PKC;

  // partitioned counting sort by col: active (mask=1) and inactive streams
  hipMemsetAsync(histA, 0, sizeof(int)*2*(NN+1), stream);
  hist2_kernel<<<(NE+255)/256, 256, 0, stream>>>(eidx, p, einv, histA, histI);
  scan2_kernel<<<2, 1024, 0, stream>>>(histA, histI);
  scatter2_kernel<<<(NE+255)/256, 256, 0, stream>>>(eidx, p, einv, eattr,
                                                    histA, histI, rcA, eaA, rcI);
  pad_kernel<<<1, 64, 0, stream>>>(histA + NN, rcA, eaA);
  cwc_kernel<<<NL, 128, 0, stream>>>(cb1, cW2, cb2, cwc);

  // single-launch bf16 weight prepack (7 regions)
  prepack_all<<<7*256, 256, 0, stream>>>(eW1, eW2, cW1, nW1, nW2, W1cp);

  hipMemcpyAsync(xA, pos, sizeof(float)*NN*3, hipMemcpyDeviceToDevice, stream);
  // fused embed + layer-0 projections
  embproj_kernel<<<NPB, 256, 0, stream>>>(x_feat, embW, embB, W1cp, eb1, W1rp,
                                          h, Abuf, Bbuf);

  float* xc = xA; float* xn = xB;
  for (int l=0;l<NL;++l){
    const size_t wofs = (size_t)l*4*4096;
    const size_t wofsn = (size_t)(l+1)*4*4096;
    hipMemsetAsync(magg, 0, sizeof(float)*(size_t)NN*HID, stream);
    hipMemcpyAsync(xn, xc, sizeof(float)*NN*3, hipMemcpyDeviceToDevice, stream);
    edge2_kernel<<<NWG, 256, 0, stream>>>(Abuf, Bbuf, xc, rcA, eaA, histA + NN,
        eW1 + (size_t)l*261*HID,
        W2p + wofs, eb2 + l*HID,
        gW  + l*HID, gb + l,
        C1p + wofs, cb1 + l*HID,
        cW2 + l*HID, cb2 + l,
        magg, xn);
    inact_kernel<<<NIB, 256, 0, stream>>>(histI + NN, rcI, xc, cwc, l, xn);
    int doProj = (l+1 < NL);
    node2f_kernel<<<NPB, 256, 0, stream>>>(h, magg,
        Wn1ap + wofs, Wn1bp + wofs, nb1 + l*HID,
        Wn2p + wofs, nb2 + l*HID,
        W1cp + (doProj?wofsn:0), eb1 + (doProj?(l+1)*HID:0),
        W1rp + (doProj?wofsn:0),
        Abuf, Bbuf, doProj);
    float* tmp = xc; xc = xn; xn = tmp;
  }
  hipMemsetAsync(sums, 0, sizeof(float)*((size_t)NG*HID + NG), stream);
  pool_kernel<<<NN/16, HID, 0, stream>>>(h, batch, sums, counts);
  out_kernel<<<NG, 64, 0, stream>>>(sums, counts, rW, rb, (float*)d_out);
}

// Round 15
// 1086.755 us; speedup vs baseline: 1.5746x; 1.0371x over previous
//
#include <hip/hip_runtime.h>

#define NN 50000
#define NE 800000
#define HID 128
#define NG 2500
#define NL 4
#define ME 64       // edges (or nodes) per block
#define HST 136     // LDS tile row stride (shorts): 272B, bank-phase 4 -> 2-way max (free)
#define NPB 782     // node blocks: ceil(50000/64)
#define NWG (NE/ME) // 12500 max edge blocks (device-side early exit past active count)
#define PKC 65536   // shorts per packed weight array: NL*4*4*HID*8

typedef __attribute__((ext_vector_type(8))) short short8v;
typedef __attribute__((ext_vector_type(4))) float f32x4;

__device__ __forceinline__ float sigf(float x){ return 1.0f/(1.0f+__expf(-x)); }
__device__ __forceinline__ float siluf(float x){ return x/(1.0f+__expf(-x)); }
__device__ __forceinline__ short bfr(float x){           // scalar f32->bf16 (RNE)
  unsigned u = __float_as_uint(x);
  u += 0x7fffu + ((u>>16)&1u);
  return (short)(u>>16);
}
__device__ __forceinline__ unsigned cvtpk(float lo, float hi){
  unsigned r;
  asm("v_cvt_pk_bf16_f32 %0, %1, %2" : "=v"(r) : "v"(lo), "v"(hi));
  return r;
}
__device__ __forceinline__ float bf2f(short s){
  return __uint_as_float(((unsigned)(unsigned short)s)<<16);
}

// ------------- partitioned counting sort of edges by col (active = mask 1) -------------
__global__ void hist2_kernel(const int* __restrict__ eidx, const float* __restrict__ p,
                             const int* __restrict__ inv,
                             int* __restrict__ histA, int* __restrict__ histI){
  int e = blockIdx.x*256 + threadIdx.x;
  if (e < NE){
    int c = eidx[NE+e];
    if (p[inv[e]] >= 0.0f) atomicAdd(&histA[c], 1);
    else                   atomicAdd(&histI[c], 1);
  }
}
// in-place exclusive scans over NN entries (block 0: histA, block 1: histI); total -> [NN]
__global__ __launch_bounds__(1024) void scan2_kernel(int* __restrict__ hA,
                                                     int* __restrict__ hI){
  int* cursor = blockIdx.x ? hI : hA;
  __shared__ int part[1024];
  int t = threadIdx.x;
  const int CH = (NN + 1023)/1024;
  int base = t*CH;
  int s = 0;
  for (int j=0;j<CH;++j){ int i=base+j; if (i<NN) s += cursor[i]; }
  part[t] = s; __syncthreads();
  for (int d=1; d<1024; d<<=1){
    int v = (t>=d) ? part[t-d] : 0;
    __syncthreads();
    part[t] += v;
    __syncthreads();
  }
  int ex = (t==0) ? 0 : part[t-1];
  for (int j=0;j<CH;++j){
    int i=base+j;
    if (i<NN){ int hv = cursor[i]; cursor[i] = ex; ex += hv; }
  }
  if (t == 1023) cursor[NN] = part[1023];   // total
}
// fused scatter + stream materialization into active / inactive sorted streams
__global__ void scatter2_kernel(const int* __restrict__ eidx, const float* __restrict__ p,
                                const int* __restrict__ inv, const float* __restrict__ ea,
                                int* __restrict__ curA, int* __restrict__ curI,
                                int2* __restrict__ rcA, float4* __restrict__ eaA,
                                int2* __restrict__ rcI){
  int e = blockIdx.x*256 + threadIdx.x;
  if (e >= NE) return;
  int r = eidx[e], c = eidx[NE+e];
  int2 rc; rc.x = r; rc.y = c;
  if (p[inv[e]] >= 0.0f){
    int pos = atomicAdd(&curA[c], 1);
    rcA[pos] = rc;
    eaA[pos] = *reinterpret_cast<const float4*>(ea + (size_t)e*4);
  } else {
    int pos = atomicAdd(&curI[c], 1);
    rcI[pos] = rc;
  }
}
// pad active stream to a multiple of 64 with dummy edges pointing at dump row NN
__global__ void pad_kernel(const int* __restrict__ naT, int2* __restrict__ rcA,
                           float4* __restrict__ eaA){
  int Na = naT[0];
  int NaP = (Na + 63) & ~63;
  int i = Na + threadIdx.x;
  if (i < NaP){
    int2 rc; rc.x = 0; rc.y = NN;   // row 0 (valid), col NN (dump row)
    rcA[i] = rc;
    float4 zz; zz.x=0.f; zz.y=0.f; zz.z=0.f; zz.w=0.f;
    eaA[i] = zz;
  }
}
// per-layer constant cw for masked edges: silu(bc1) . Wc2 + cb2 (f32 exact)
__global__ void cwc_kernel(const float* __restrict__ cb1, const float* __restrict__ cW2,
                           const float* __restrict__ cb2, float* __restrict__ cwc){
  int l = blockIdx.x, o = threadIdx.x;   // 128 threads
  float v = siluf(cb1[l*HID+o]) * cW2[l*HID+o];
  #pragma unroll
  for (int off=32; off>0; off>>=1) v += __shfl_down(v, off);
  __shared__ float red[2];
  if ((o & 63) == 0) red[o>>6] = v;
  __syncthreads();
  if (o == 0) cwc[l] = red[0] + red[1] + cb2[l];
}

// ---- single-launch weight prepack: 7 regions, dst contiguous at stride PKC ----
__global__ void prepack_all(const float* __restrict__ eW1, const float* __restrict__ eW2,
                            const float* __restrict__ cW1, const float* __restrict__ nW1,
                            const float* __restrict__ nW2, short* __restrict__ dst0){
  int region = blockIdx.x >> 8;                       // PKC/256 = 256 blocks per region
  int idx = ((blockIdx.x & 255) << 8) + threadIdx.x;
  const float* W; int Ktot, roff;
  switch(region){
    case 0: W=eW1; Ktot=261; roff=0;   break;
    case 1: W=eW1; Ktot=261; roff=128; break;
    case 2: W=eW2; Ktot=128; roff=0;   break;
    case 3: W=cW1; Ktot=128; roff=0;   break;
    case 4: W=nW1; Ktot=256; roff=0;   break;
    case 5: W=nW1; Ktot=256; roff=128; break;
    default: W=nW2; Ktot=128; roff=0;  break;
  }
  int kk8 = idx & 7;
  int o   = (idx>>3) & 127;
  int q   = (idx>>10) & 3;
  int ks  = (idx>>12) & 3;
  int l   = idx >> 14;
  int k = roff + ks*32 + q*8 + kk8;
  float v = (k < Ktot) ? W[((size_t)l*Ktot + k)*HID + o] : 0.0f;
  dst0[(size_t)region*PKC + idx] = bfr(v);
}

// ---------------- MFMA tile-GEMM: [64 x 128] (LDS bf16) @ [128 x 128] (prepacked) ----
__device__ __forceinline__ void gemm64(const short* As, int astride,
                                       const short* Wp, int nks,
                                       short* bkS, f32x4 acc[2][4], int t)
{
  const int lane = t & 63, w = t >> 6;
  const int q = lane >> 4, fr = lane & 15;
  const int erow = (w & 1) * 32;
  const int ocol = (w >> 1) * 64;
  const int4* g = reinterpret_cast<const int4*>(Wp);
  int4* bkw = reinterpret_cast<int4*>(bkS);
  int4 p0 = g[t], p1 = g[256 + t];
  for (int ks = 0; ks < nks; ++ks){
    const int buf = (ks & 1) * 512;            // int4 units (4096 shorts)
    bkw[buf + t] = p0; bkw[buf + 256 + t] = p1;
    __syncthreads();
    if (ks + 1 < nks){ p0 = g[(ks+1)*512 + t]; p1 = g[(ks+1)*512 + 256 + t]; }
    const short* bb = bkS + buf*8 + q*1024;
    short8v a[2], b[4];
    #pragma unroll
    for (int et=0; et<2; ++et)
      a[et] = *reinterpret_cast<const short8v*>(As + (erow + et*16 + fr)*astride + ks*32 + q*8);
    #pragma unroll
    for (int ot=0; ot<4; ++ot)
      b[ot] = *reinterpret_cast<const short8v*>(bb + (ocol + ot*16 + fr)*8);
    #pragma unroll
    for (int et=0; et<2; ++et)
      #pragma unroll
      for (int ot=0; ot<4; ++ot)
        acc[et][ot] = __builtin_amdgcn_mfma_f32_16x16x32_bf16(a[et], b[ot], acc[et][ot], 0, 0, 0);
  }
  __syncthreads();
}

// acc -> silu(scale*acc + bias) -> bf16 LDS tile [64][HST]; scaleS==nullptr -> scale=1
__device__ __forceinline__ void epilogue_store(const f32x4 acc[2][4],
                                               const float* __restrict__ bias,
                                               const float* __restrict__ scaleS,
                                               short* dst, int t)
{
  const int lane = t & 63, w = t >> 6;
  const int q = lane >> 4, fr = lane & 15;
  #pragma unroll
  for (int et=0; et<2; ++et){
    const int e0 = (w&1)*32 + et*16 + q*4;
    float s0=1.f,s1=1.f,s2=1.f,s3=1.f;
    if (scaleS){ s0=scaleS[e0]; s1=scaleS[e0+1]; s2=scaleS[e0+2]; s3=scaleS[e0+3]; }
    #pragma unroll
    for (int ot=0; ot<4; ++ot){
      int o = (w>>1)*64 + ot*16 + fr;
      float bv = bias[o];
      unsigned p01 = cvtpk(siluf(fmaf(s0,acc[et][ot][0],bv)), siluf(fmaf(s1,acc[et][ot][1],bv)));
      unsigned p23 = cvtpk(siluf(fmaf(s2,acc[et][ot][2],bv)), siluf(fmaf(s3,acc[et][ot][3],bv)));
      dst[(e0+0)*HST + o] = (short)p01;
      dst[(e0+1)*HST + o] = (short)(p01>>16);
      dst[(e0+2)*HST + o] = (short)p23;
      dst[(e0+3)*HST + o] = (short)(p23>>16);
    }
  }
}

// ---- fused embed + layer-0 node projections ----
__global__ __launch_bounds__(256) void embproj_kernel(
    const float* __restrict__ xf, const float* __restrict__ embW,
    const float* __restrict__ embB,
    const short* __restrict__ Wcp, const float* __restrict__ b1,
    const short* __restrict__ Wrp,
    float* __restrict__ h, short* __restrict__ A, short* __restrict__ B)
{
  __shared__ __align__(16) short hT[ME*HST];
  __shared__ __align__(16) short bkS[2*4096];
  __shared__ float xfS[ME][12];
  __shared__ float wS[11][HID];
  __shared__ float bS[HID];
  const int t = threadIdx.x;
  const int n0 = blockIdx.x * ME;
  for (int i = t; i < ME*11; i += 256){
    int nl = i / 11, ii = i % 11;
    int n = n0 + nl; if (n >= NN) n = NN-1;
    xfS[nl][ii] = xf[(size_t)n*11 + ii];
  }
  for (int i = t; i < 11*HID; i += 256) wS[i>>7][i&127] = embW[i];
  if (t < HID) bS[t] = embB[t];
  __syncthreads();
  {
    int nl = t >> 2, seg = t & 3;
    int n = n0 + nl;
    float hv[32];
    #pragma unroll
    for (int j=0;j<32;++j){
      int o = seg*32 + j;
      float s = bS[o];
      #pragma unroll
      for (int i=0;i<11;++i) s = fmaf(xfS[nl][i], wS[i][o], s);
      hv[j] = s;
    }
    if (n < NN){
      float4* hp = reinterpret_cast<float4*>(h + (size_t)n*HID + seg*32);
      #pragma unroll
      for (int j=0;j<8;++j){
        float4 u; u.x=hv[j*4]; u.y=hv[j*4+1]; u.z=hv[j*4+2]; u.w=hv[j*4+3];
        hp[j] = u;
      }
    }
    #pragma unroll
    for (int bq=0;bq<4;++bq){
      int4 sv;
      sv.x = (int)cvtpk(hv[bq*8+0],hv[bq*8+1]); sv.y = (int)cvtpk(hv[bq*8+2],hv[bq*8+3]);
      sv.z = (int)cvtpk(hv[bq*8+4],hv[bq*8+5]); sv.w = (int)cvtpk(hv[bq*8+6],hv[bq*8+7]);
      *reinterpret_cast<int4*>(&hT[nl*HST + seg*32 + bq*8]) = sv;
    }
  }
  f32x4 z = {0.f,0.f,0.f,0.f};
  f32x4 accA[2][4], accB[2][4];
  #pragma unroll
  for (int i=0;i<2;++i){ accA[i][0]=z;accA[i][1]=z;accA[i][2]=z;accA[i][3]=z;
                         accB[i][0]=z;accB[i][1]=z;accB[i][2]=z;accB[i][3]=z; }
  gemm64(hT, HST, Wcp, 4, bkS, accA, t);
  gemm64(hT, HST, Wrp, 4, bkS, accB, t);
  const int lane = t & 63, w = t >> 6;
  const int q = lane >> 4, fr = lane & 15;
  #pragma unroll
  for (int et=0; et<2; ++et){
    int e0 = (w&1)*32 + et*16 + q*4;
    #pragma unroll
    for (int ot=0; ot<4; ++ot){
      int o = (w>>1)*64 + ot*16 + fr;
      float bv = b1[o];
      #pragma unroll
      for (int r=0;r<4;++r){
        int n = n0 + e0 + r;
        if (n < NN){
          A[(size_t)n*HID + o] = bfr(accA[et][ot][r] + bv);
          B[(size_t)n*HID + o] = bfr(accB[et][ot][r]);
        }
      }
    }
  }
}

// ------- edge kernel: active blocks = full pipeline; tail blocks = inactive streaming -------
__global__ __launch_bounds__(256) void edge2_kernel(
    const short* __restrict__ A, const short* __restrict__ B,
    const float* __restrict__ x,
    const int2* __restrict__ rcS, const float4* __restrict__ eaS,
    const int* __restrict__ naT,
    const int* __restrict__ niT, const int2* __restrict__ rcI,
    const float* __restrict__ cwcL,
    const float* __restrict__ wrow,   // eW1 + l*261*128 : rows 256..260 = wd, wea
    const short* __restrict__ W2p, const float* __restrict__ b2,
    const float* __restrict__ Wg, const float* __restrict__ bg,
    const short* __restrict__ C1p, const float* __restrict__ bc1,
    const float* __restrict__ Wc2, const float* __restrict__ cb2,
    float* __restrict__ magg, float* __restrict__ xout)
{
  __shared__ __align__(16) short hidS[ME*HST];   // hidden1 -> m_pre (kept) -> hidden2
  __shared__ __align__(16) short bkS[2*4096];
  __shared__ float wdS[HID], wgS[HID], wc2S[HID];
  __shared__ float weaS[4][HID];
  __shared__ float scaleS[ME], cwS[ME], distS[ME], cdS[ME][3];
  __shared__ int colS[ME];

  const int t = threadIdx.x;
  const int nab = (naT[0] + 63) >> 6;            // number of active blocks
  if ((int)blockIdx.x >= nab){
    // ---- tail blocks: inactive edges, xout[col] += coord_diff * cw_const ----
    int Ni = niT[0];
    int base = ((blockIdx.x - nab)*256 + t)*8;
    if (base >= Ni) return;
    const float cw = cwcL[0];
    int end = base + 8; if (end > Ni) end = Ni;
    int curc = rcI[base].y;
    float ax=0.f, ay=0.f, az=0.f;
    for (int i=base;i<end;++i){
      int2 rc = rcI[i];
      if (rc.y != curc){
        atomicAdd(&xout[curc*3+0], ax);
        atomicAdd(&xout[curc*3+1], ay);
        atomicAdd(&xout[curc*3+2], az);
        ax=0.f; ay=0.f; az=0.f; curc = rc.y;
      }
      float dx = x[rc.y*3+0]-x[rc.x*3+0];
      float dy = x[rc.y*3+1]-x[rc.x*3+1];
      float dz = x[rc.y*3+2]-x[rc.x*3+2];
      ax = fmaf(dx,cw,ax); ay = fmaf(dy,cw,ay); az = fmaf(dz,cw,az);
    }
    atomicAdd(&xout[curc*3+0], ax);
    atomicAdd(&xout[curc*3+1], ay);
    atomicAdd(&xout[curc*3+2], az);
    return;
  }
  // ---- active blocks: dynamic-range bijective XCD swizzle ----
  const int qq = nab >> 3, rr = nab & 7;
  const int xcd = blockIdx.x & 7, sub = blockIdx.x >> 3;
  const int bid = (xcd < rr ? xcd*(qq+1) : rr*(qq+1) + (xcd-rr)*qq) + sub;
  const int i0 = bid * ME;

  // issue per-thread gathers early (4 threads/edge, 32 channels each)
  const int el = t >> 2, seg = t & 3;
  const int2 rc = rcS[i0 + el];
  const int4* Ap = reinterpret_cast<const int4*>(A + (size_t)rc.y*HID + seg*32);
  const int4* Bp = reinterpret_cast<const int4*>(B + (size_t)rc.x*HID + seg*32);
  int4 av0=Ap[0], av1=Ap[1], av2=Ap[2], av3=Ap[3];
  int4 bv0=Bp[0], bv1=Bp[1], bv2=Bp[2], bv3=Bp[3];
  float4 eav = eaS[i0 + el];

  if (t < HID){
    wdS[t] = wrow[256*HID + t];
    wgS[t] = Wg[t]; wc2S[t] = Wc2[t];
    #pragma unroll
    for (int j=0;j<4;++j) weaS[j][t] = wrow[(257+j)*HID + t];
  }
  if (t < ME){
    int2 rc2 = rcS[i0 + t];
    colS[t] = rc2.y;
    float dx = x[rc2.y*3+0]-x[rc2.x*3+0];
    float dy = x[rc2.y*3+1]-x[rc2.x*3+1];
    float dz = x[rc2.y*3+2]-x[rc2.x*3+2];
    cdS[t][0]=dx; cdS[t][1]=dy; cdS[t][2]=dz;
    distS[t] = sqrtf(dx*dx+dy*dy+dz*dz);
  }
  __syncthreads();

  // hidden1 = silu(A[col] + B[row] + dist*wd + ea@wea)
  {
    float de = distS[el];
    const int4 avs[4] = {av0,av1,av2,av3};
    const int4 bvs[4] = {bv0,bv1,bv2,bv3};
    #pragma unroll
    for (int bq=0;bq<4;++bq){
      short8v a8 = *reinterpret_cast<const short8v*>(&avs[bq]);
      short8v b8 = *reinterpret_cast<const short8v*>(&bvs[bq]);
      float f[8];
      #pragma unroll
      for (int j=0;j<8;++j){
        int o = seg*32 + bq*8 + j;
        float v = bf2f(a8[j]) + bf2f(b8[j]) + de*wdS[o]
                + eav.x*weaS[0][o] + eav.y*weaS[1][o]
                + eav.z*weaS[2][o] + eav.w*weaS[3][o];
        f[j] = siluf(v);
      }
      int4 sv;
      sv.x = (int)cvtpk(f[0],f[1]); sv.y = (int)cvtpk(f[2],f[3]);
      sv.z = (int)cvtpk(f[4],f[5]); sv.w = (int)cvtpk(f[6],f[7]);
      *reinterpret_cast<int4*>(&hidS[el*HST + seg*32 + bq*8]) = sv;
    }
  }
  // gemm64's first loop-top barrier publishes hidS

  f32x4 z = {0.f,0.f,0.f,0.f};
  f32x4 acc2[2][4];
  #pragma unroll
  for (int i=0;i<2;++i){ acc2[i][0]=z; acc2[i][1]=z; acc2[i][2]=z; acc2[i][3]=z; }
  gemm64(hidS, HST, W2p, 4, bkS, acc2, t);
  epilogue_store(acc2, b2, nullptr, hidS, t);     // m_pre (in-place)
  __syncthreads();                                // publish m_pre

  // gate = sigmoid(m_pre . Wg + bg)   (active edges: mask == 1)
  {
    int eg = t >> 2, g = t & 3;
    float p = 0.f;
    #pragma unroll
    for (int bq=0;bq<4;++bq){
      short8v s = *reinterpret_cast<const short8v*>(&hidS[eg*HST + g*32 + bq*8]);
      #pragma unroll
      for (int j=0;j<8;++j) p += bf2f(s[j]) * wgS[g*32 + bq*8 + j];
    }
    p += __shfl_xor(p, 1); p += __shfl_xor(p, 2);
    if (g == 0) scaleS[eg] = sigf(p + bg[0]);
  }
  __syncthreads();                                // publish scaleS

  // magg[col] += m_pre * scale (segmented; cols sorted)
  {
    int o = t & 127, half = t >> 7;
    int ib = half*32;
    float accv = 0.f;
    int curc = colS[ib];
    #pragma unroll 4
    for (int j=0;j<32;++j){
      int i = ib + j;
      int cc = colS[i];
      if (cc != curc){
        atomicAdd(&magg[(size_t)curc*HID + o], accv);
        accv = 0.f; curc = cc;
      }
      accv += bf2f(hidS[i*HST + o]) * scaleS[i];
    }
    atomicAdd(&magg[(size_t)curc*HID + o], accv);
  }

  // hidden2 = silu(scale * (m_pre @ Wc1) + bc1)
  f32x4 acc3[2][4];
  #pragma unroll
  for (int i=0;i<2;++i){ acc3[i][0]=z; acc3[i][1]=z; acc3[i][2]=z; acc3[i][3]=z; }
  gemm64(hidS, HST, C1p, 4, bkS, acc3, t);
  epilogue_store(acc3, bc1, scaleS, hidS, t);     // hidden2 (in-place)
  __syncthreads();                                // publish hidden2

  // cw = hidden2 . Wc2 + cb2
  {
    int eg = t >> 2, g = t & 3;
    float p = 0.f;
    #pragma unroll
    for (int bq=0;bq<4;++bq){
      short8v s = *reinterpret_cast<const short8v*>(&hidS[eg*HST + g*32 + bq*8]);
      #pragma unroll
      for (int j=0;j<8;++j) p += bf2f(s[j]) * wc2S[g*32 + bq*8 + j];
    }
    p += __shfl_xor(p, 1); p += __shfl_xor(p, 2);
    if (g == 0) cwS[eg] = p + cb2[0];
  }
  __syncthreads();                                // publish cwS

  // x_out[col] += coord_diff * cw (segmented)
  if (t < 6){
    int d = t % 3, half = t / 3;
    int ib = half*32;
    float accx = 0.f;
    int curc = colS[ib];
    for (int j=0;j<32;++j){
      int i = ib + j;
      int cc = colS[i];
      if (cc != curc){
        atomicAdd(&xout[curc*3+d], accx);
        accx = 0.f; curc = cc;
      }
      accx += cdS[i][d] * cwS[i];
    }
    atomicAdd(&xout[curc*3+d], accx);
  }
}

// ---- fused node MLP + next-layer projections ----
__global__ __launch_bounds__(256) void node2f_kernel(
    float* __restrict__ h, const float* __restrict__ magg,
    const short* __restrict__ W1ap, const short* __restrict__ W1bp,
    const float* __restrict__ bn1,
    const short* __restrict__ Wn2p, const float* __restrict__ bn2,
    const short* __restrict__ Wcp, const float* __restrict__ b1n,
    const short* __restrict__ Wrp,
    short* __restrict__ A, short* __restrict__ B, int doProj)
{
  __shared__ __align__(16) short hT[ME*HST];
  __shared__ __align__(16) short mT[ME*HST];
  __shared__ __align__(16) short bkS[2*4096];
  const int t = threadIdx.x;
  const int n0 = blockIdx.x * ME;
  {
    int nl = t >> 2, seg = t & 3;
    int n = n0 + nl; if (n >= NN) n = NN-1;
    const float4* hp = reinterpret_cast<const float4*>(h + (size_t)n*HID + seg*32);
    const float4* mp = reinterpret_cast<const float4*>(magg + (size_t)n*HID + seg*32);
    #pragma unroll
    for (int bq=0;bq<4;++bq){
      float4 u = hp[bq*2], v = hp[bq*2+1];
      int4 sv;
      sv.x = (int)cvtpk(u.x,u.y); sv.y = (int)cvtpk(u.z,u.w);
      sv.z = (int)cvtpk(v.x,v.y); sv.w = (int)cvtpk(v.z,v.w);
      *reinterpret_cast<int4*>(&hT[nl*HST + seg*32 + bq*8]) = sv;
      float4 u2 = mp[bq*2], v2 = mp[bq*2+1];
      int4 sv2;
      sv2.x = (int)cvtpk(u2.x,u2.y); sv2.y = (int)cvtpk(u2.z,u2.w);
      sv2.z = (int)cvtpk(v2.x,v2.y); sv2.w = (int)cvtpk(v2.z,v2.w);
      *reinterpret_cast<int4*>(&mT[nl*HST + seg*32 + bq*8]) = sv2;
    }
  }
  f32x4 z = {0.f,0.f,0.f,0.f};
  f32x4 acc[2][4];
  #pragma unroll
  for (int i=0;i<2;++i){ acc[i][0]=z; acc[i][1]=z; acc[i][2]=z; acc[i][3]=z; }
  gemm64(hT, HST, W1ap, 4, bkS, acc, t);
  gemm64(mT, HST, W1bp, 4, bkS, acc, t);        // accumulates
  epilogue_store(acc, bn1, nullptr, mT, t);      // silu1 -> mT
  __syncthreads();

  f32x4 acc2[2][4];
  #pragma unroll
  for (int i=0;i<2;++i){ acc2[i][0]=z; acc2[i][1]=z; acc2[i][2]=z; acc2[i][3]=z; }
  gemm64(mT, HST, Wn2p, 4, bkS, acc2, t);

  const int lane = t & 63, w = t >> 6;
  const int q = lane >> 4, fr = lane & 15;
  #pragma unroll
  for (int et=0; et<2; ++et){
    int e0 = (w&1)*32 + et*16 + q*4;
    #pragma unroll
    for (int ot=0; ot<4; ++ot){
      int o = (w>>1)*64 + ot*16 + fr;
      float bv = bn2[o];
      float hn[4];
      #pragma unroll
      for (int r=0;r<4;++r){
        int n = n0 + e0 + r;
        float hv = 0.f;
        if (n < NN){
          size_t idx = (size_t)n*HID + o;
          hv = h[idx] + acc2[et][ot][r] + bv;
          h[idx] = hv;
        }
        hn[r] = hv;
      }
      if (doProj){
        unsigned p01 = cvtpk(hn[0],hn[1]), p23 = cvtpk(hn[2],hn[3]);
        hT[(e0+0)*HST + o] = (short)p01;
        hT[(e0+1)*HST + o] = (short)(p01>>16);
        hT[(e0+2)*HST + o] = (short)p23;
        hT[(e0+3)*HST + o] = (short)(p23>>16);
      }
    }
  }
  if (!doProj) return;
  // (gemm64's loop-top barrier publishes hT)

  f32x4 accA[2][4], accB[2][4];
  #pragma unroll
  for (int i=0;i<2;++i){ accA[i][0]=z;accA[i][1]=z;accA[i][2]=z;accA[i][3]=z;
                         accB[i][0]=z;accB[i][1]=z;accB[i][2]=z;accB[i][3]=z; }
  gemm64(hT, HST, Wcp, 4, bkS, accA, t);
  gemm64(hT, HST, Wrp, 4, bkS, accB, t);
  #pragma unroll
  for (int et=0; et<2; ++et){
    int e0 = (w&1)*32 + et*16 + q*4;
    #pragma unroll
    for (int ot=0; ot<4; ++ot){
      int o = (w>>1)*64 + ot*16 + fr;
      float bv = b1n[o];
      #pragma unroll
      for (int r=0;r<4;++r){
        int n = n0 + e0 + r;
        if (n < NN){
          A[(size_t)n*HID + o] = bfr(accA[et][ot][r] + bv);
          B[(size_t)n*HID + o] = bfr(accB[et][ot][r]);
        }
      }
    }
  }
}

__global__ void pool_kernel(const float* __restrict__ h, const int* __restrict__ batch,
                            float* __restrict__ sums, float* __restrict__ counts){
  int o  = threadIdx.x;
  int n0 = blockIdx.x * 16;
  int curg = batch[n0];
  float accv = 0.f, cnt = 0.f;
  for (int j=0;j<16;++j){
    int n = n0 + j;
    int g = batch[n];
    if (g != curg){
      atomicAdd(&sums[(size_t)curg*HID+o], accv);
      if (o==0) atomicAdd(&counts[curg], cnt);
      accv = 0.f; cnt = 0.f; curg = g;
    }
    accv += h[(size_t)n*HID+o];
    cnt  += 1.f;
  }
  atomicAdd(&sums[(size_t)curg*HID+o], accv);
  if (o==0) atomicAdd(&counts[curg], cnt);
}

__global__ void out_kernel(const float* __restrict__ sums, const float* __restrict__ counts,
                           const float* __restrict__ rW, const float* __restrict__ rb,
                           float* __restrict__ out){
  int g = blockIdx.x; int t = threadIdx.x;
  float v = sums[(size_t)g*HID + t]*rW[t] + sums[(size_t)g*HID + 64 + t]*rW[64+t];
  #pragma unroll
  for (int off=32; off>0; off>>=1) v += __shfl_down(v, off);
  if (t==0) out[g] = v / fmaxf(counts[g], 1.0f) + rb[0];
}

extern "C" void kernel_launch(void* const* d_in, const int* in_sizes, int n_in,
                              void* d_out, int out_size, void* d_ws, size_t ws_size,
                              hipStream_t stream)
{
  const float* x_feat = (const float*)d_in[0];
  const float* pos    = (const float*)d_in[1];
  const float* eattr  = (const float*)d_in[2];
  const float* p      = (const float*)d_in[3];
  const float* embW   = (const float*)d_in[4];
  const float* embB   = (const float*)d_in[5];
  const float* eW1    = (const float*)d_in[6];
  const float* eb1    = (const float*)d_in[7];
  const float* eW2    = (const float*)d_in[8];
  const float* eb2    = (const float*)d_in[9];
  const float* gW     = (const float*)d_in[10];
  const float* gb     = (const float*)d_in[11];
  const float* nW1    = (const float*)d_in[12];
  const float* nb1    = (const float*)d_in[13];
  const float* nW2    = (const float*)d_in[14];
  const float* nb2    = (const float*)d_in[15];
  const float* cW1    = (const float*)d_in[16];
  const float* cb1    = (const float*)d_in[17];
  const float* cW2    = (const float*)d_in[18];
  const float* cb2    = (const float*)d_in[19];
  const float* rW     = (const float*)d_in[20];
  const float* rb     = (const float*)d_in[21];
  const int* eidx     = (const int*)d_in[22];
  const int* einv     = (const int*)d_in[23];
  const int* batch    = (const int*)d_in[24];

  float* ws = (float*)d_ws;
  float* h      = ws;  ws += (size_t)NN*HID;
  float* magg   = ws;  ws += (size_t)(NN+1)*HID;       // +dump row
  float* xA     = ws;  ws += (size_t)(NN+1)*3;         // +dump row
  float* xB     = ws;  ws += (size_t)(NN+1)*3;
  float* sums   = ws;  ws += (size_t)NG*HID;
  float* counts = ws;  ws += NG;
  float* cwc    = ws;  ws += 4;
  int*   histA  = (int*)ws;  ws += NN+1;               // [NN] = Na
  int*   histI  = (int*)ws;  ws += NN+1;               // [NN] = Ni
  int2*  rcA    = (int2*)ws;  ws += (size_t)NE*2;
  int2*  rcI    = (int2*)ws;  ws += (size_t)NE*2;
  float4* eaA   = (float4*)ws; ws += (size_t)NE*4;
  short* Abuf = (short*)ws;  ws += (size_t)(NN+1)*HID/2;   // +dump row
  short* Bbuf = (short*)ws;  ws += (size_t)(NN+1)*HID/2;
  short* W1cp  = (short*)ws;                           // 7 contiguous arrays, stride PKC
  short* W1rp  = W1cp  + PKC;
  short* W2p   = W1rp  + PKC;
  short* C1p   = W2p   + PKC;
  short* Wn1ap = C1p   + PKC;
  short* Wn1bp = Wn1ap + PKC;
  short* Wn2p  = Wn1bp + PKC;

  // partitioned counting sort by col: active (mask=1) and inactive streams
  hipMemsetAsync(histA, 0, sizeof(int)*2*(NN+1), stream);
  hist2_kernel<<<(NE+255)/256, 256, 0, stream>>>(eidx, p, einv, histA, histI);
  scan2_kernel<<<2, 1024, 0, stream>>>(histA, histI);
  scatter2_kernel<<<(NE+255)/256, 256, 0, stream>>>(eidx, p, einv, eattr,
                                                    histA, histI, rcA, eaA, rcI);
  pad_kernel<<<1, 64, 0, stream>>>(histA + NN, rcA, eaA);
  cwc_kernel<<<NL, 128, 0, stream>>>(cb1, cW2, cb2, cwc);

  // single-launch bf16 weight prepack (7 regions)
  prepack_all<<<7*256, 256, 0, stream>>>(eW1, eW2, cW1, nW1, nW2, W1cp);

  hipMemcpyAsync(xA, pos, sizeof(float)*NN*3, hipMemcpyDeviceToDevice, stream);
  // fused embed + layer-0 projections
  embproj_kernel<<<NPB, 256, 0, stream>>>(x_feat, embW, embB, W1cp, eb1, W1rp,
                                          h, Abuf, Bbuf);

  float* xc = xA; float* xn = xB;
  for (int l=0;l<NL;++l){
    const size_t wofs = (size_t)l*4*4096;
    const size_t wofsn = (size_t)(l+1)*4*4096;
    hipMemsetAsync(magg, 0, sizeof(float)*(size_t)NN*HID, stream);
    hipMemcpyAsync(xn, xc, sizeof(float)*NN*3, hipMemcpyDeviceToDevice, stream);
    edge2_kernel<<<NWG, 256, 0, stream>>>(Abuf, Bbuf, xc, rcA, eaA, histA + NN,
        histI + NN, rcI, cwc + l,
        eW1 + (size_t)l*261*HID,
        W2p + wofs, eb2 + l*HID,
        gW  + l*HID, gb + l,
        C1p + wofs, cb1 + l*HID,
        cW2 + l*HID, cb2 + l,
        magg, xn);
    int doProj = (l+1 < NL);
    node2f_kernel<<<NPB, 256, 0, stream>>>(h, magg,
        Wn1ap + wofs, Wn1bp + wofs, nb1 + l*HID,
        Wn2p + wofs, nb2 + l*HID,
        W1cp + (doProj?wofsn:0), eb1 + (doProj?(l+1)*HID:0),
        W1rp + (doProj?wofsn:0),
        Abuf, Bbuf, doProj);
    float* tmp = xc; xc = xn; xn = tmp;
  }
  hipMemsetAsync(sums, 0, sizeof(float)*((size_t)NG*HID + NG), stream);
  pool_kernel<<<NN/16, HID, 0, stream>>>(h, batch, sums, counts);
  out_kernel<<<NG, 64, 0, stream>>>(sums, counts, rW, rb, (float*)d_out);
}